// Round 8
// baseline (161.601 us; speedup 1.0000x reference)
//
#include <hip/hip_runtime.h>
#include <hip/hip_bf16.h>

// NonLocal block == flash attention (4 heads, N=4096, D=128) + 1x1-conv GEMMs.
// Round 8: V read direct from L2 (early-issued reg prefetch; all block waves
// share L2 lines), vbuf removed (LDS 24KB); out_fused split across o (2x grid).

typedef float f32x4 __attribute__((ext_vector_type(4)));
typedef short s16x8 __attribute__((ext_vector_type(8)));

#define B_  4
#define C_  256
#define CI_ 128
#define N_  4096

// workspace layout (bytes)
#define OFF_XT   0ull                    // bf16 [B][N][C]   8 MB
#define OFF_Q    (8ull  << 20)           // bf16 [B][N][CI]  4 MB (theta^T, scaled)
#define OFF_K    (12ull << 20)           // bf16 [B][N][CI]  4 MB (phi^T)
#define OFF_G    (16ull << 20)           // bf16 [B][CI][N]  4 MB (g, V^T layout)
#define OFF_WQK  (24ull << 20)
#define OFF_WG   (OFF_WQK + 131072)
#define OFF_WOUT (OFF_WG  + 65536)
#define OFF_BQK  (OFF_WOUT + 65536)
#define OFF_BG   (OFF_BQK + 1024)
#define OFF_BOUT (OFF_BG  + 512)
#define OFF_END  (OFF_BOUT + 1024)       // = 25430528

__device__ inline f32x4 mfma16(s16x8 a, s16x8 b, f32x4 c) {
    return __builtin_amdgcn_mfma_f32_16x16x32_bf16(a, b, c, 0, 0, 0);
}
__device__ inline s16x8 ld8(const __hip_bfloat16* p) { return *(const s16x8*)p; }
__device__ inline float b2f(short u) {
    return __uint_as_float(((unsigned int)(unsigned short)u) << 16);
}
__device__ inline unsigned int pk2(float a, float b) {
    __hip_bfloat162 h;
    h.x = __float2bfloat16(a); h.y = __float2bfloat16(b);
    return *(unsigned int*)&h;
}
__device__ inline void gload_lds16(const void* g, void* l) {
    __builtin_amdgcn_global_load_lds(
        (const __attribute__((address_space(1))) unsigned int*)g,
        (__attribute__((address_space(3))) unsigned int*)l, 16, 0, 0);
}
__device__ inline float fexp2(float x) { return __builtin_amdgcn_exp2f(x); }

// ---------------- weight prep: fp32 -> bf16; fold log2e/sqrt(Ci) into theta
__global__ void prep_weights(const float* wg, const float* bg,
                             const float* wt, const float* bt,
                             const float* wp, const float* bp,
                             const float* wo, const float* bo, char* ws) {
    __hip_bfloat16* Wqk  = (__hip_bfloat16*)(ws + OFF_WQK);
    __hip_bfloat16* Wg   = (__hip_bfloat16*)(ws + OFF_WG);
    __hip_bfloat16* Wout = (__hip_bfloat16*)(ws + OFF_WOUT);
    float* Bqk  = (float*)(ws + OFF_BQK);
    float* Bg   = (float*)(ws + OFF_BG);
    float* Bout = (float*)(ws + OFF_BOUT);
    const float rs = 0.08838834764831845f * 1.4426950408889634f;  // 1/sqrt(128)*log2(e)
    int idx = blockIdx.x * 256 + threadIdx.x;
    if (idx < 65536) {
        int r = idx >> 8, c = idx & 255;
        float v = (r < 128) ? wt[r * 256 + c] * rs : wp[(r - 128) * 256 + c];
        Wqk[idx] = __float2bfloat16(v);
    }
    if (idx < 32768) {
        Wg[idx]   = __float2bfloat16(wg[idx]);
        Wout[idx] = __float2bfloat16(wo[idx]);
    }
    if (idx < 256) { Bqk[idx] = (idx < 128) ? bt[idx] * rs : bp[idx - 128]; Bout[idx] = bo[idx]; }
    if (idx < 128) Bg[idx] = bg[idx];
}

// ---------------- x [B][C][N] f32 -> XT [B][N][C] bf16 -------------------
__global__ __launch_bounds__(256) void transpose_x(const float* x, char* ws) {
    __shared__ float tile[32][33];
    __hip_bfloat16* XT = (__hip_bfloat16*)(ws + OFF_XT);
    int b = blockIdx.z;
    int n0 = blockIdx.x * 32, c0 = blockIdx.y * 32;
    int tx = threadIdx.x & 31, ty = threadIdx.x >> 5;
#pragma unroll
    for (int r = 0; r < 4; r++)
        tile[ty + 8 * r][tx] = x[(size_t)(b * C_ + c0 + ty + 8 * r) * N_ + n0 + tx];
    __syncthreads();
#pragma unroll
    for (int r = 0; r < 4; r++)
        XT[(size_t)(b * N_ + n0 + ty + 8 * r) * C_ + c0 + tx] =
            __float2bfloat16(tile[tx][ty + 8 * r]);
}

// ---------------- fused projection: Q, K, G from XT in one pass ------------
__global__ __launch_bounds__(256) void proj(char* ws) {
    const __hip_bfloat16* XT  = (const __hip_bfloat16*)(ws + OFF_XT);
    const __hip_bfloat16* Wqk = (const __hip_bfloat16*)(ws + OFF_WQK);
    const __hip_bfloat16* Wg  = (const __hip_bfloat16*)(ws + OFF_WG);
    const float* Bqk = (const float*)(ws + OFF_BQK);
    const float* Bg  = (const float*)(ws + OFF_BG);
    __hip_bfloat16* Q  = (__hip_bfloat16*)(ws + OFF_Q);
    __hip_bfloat16* Kb = (__hip_bfloat16*)(ws + OFF_K);
    __hip_bfloat16* G  = (__hip_bfloat16*)(ws + OFF_G);

    __shared__ char at[32 * 512];   // [32 n][256 c] bf16, 16B slots XOR-swizzled

    int b = blockIdx.y, n0 = blockIdx.x * 32;
    int w = threadIdx.x >> 6, l = threadIdx.x & 63, lr = l & 15, lg = l >> 4;

    const char* xbase = (const char*)(XT + ((size_t)b * N_ + n0) * C_);
#pragma unroll
    for (int p = 0; p < 4; p++) {
        int row = p * 8 + w * 2 + (l >> 5);
        int slot = l & 31;
        const char* src = xbase + row * 512 + ((slot ^ (row & 7)) << 4);
        gload_lds16(src, &at[(p * 8 + w * 2) * 512]);
    }
    __syncthreads();

    f32x4 acc[4][2] = {};    // QK path: [of][nf]
    f32x4 accg[2][2] = {};   // G  path: [og][nf]
    int o0q = w * 64, o0g = w * 32;
#pragma unroll
    for (int kk = 0; kk < 8; kk++) {
        s16x8 a[2];
#pragma unroll
        for (int nf = 0; nf < 2; nf++) {
            int row = nf * 16 + lr;
            int s = (4 * kk + lg) ^ (row & 7);
            a[nf] = *(const s16x8*)(&at[row * 512 + s * 16]);
        }
#pragma unroll
        for (int of = 0; of < 4; of++) {
            s16x8 bb = ld8(Wqk + (size_t)(o0q + 16 * of + lr) * C_ + kk * 32 + lg * 8);
            acc[of][0] = mfma16(a[0], bb, acc[of][0]);
            acc[of][1] = mfma16(a[1], bb, acc[of][1]);
        }
#pragma unroll
        for (int og = 0; og < 2; og++) {
            s16x8 ag = ld8(Wg + (size_t)(o0g + 16 * og + lr) * C_ + kk * 32 + lg * 8);
            accg[og][0] = mfma16(ag, a[0], accg[og][0]);
            accg[og][1] = mfma16(ag, a[1], accg[og][1]);
        }
    }
#pragma unroll
    for (int of = 0; of < 4; of++) {
        int o = o0q + 16 * of + lr;
        float bias = Bqk[o];
#pragma unroll
        for (int nf = 0; nf < 2; nf++) {
#pragma unroll
            for (int i = 0; i < 4; i++) {
                int n = n0 + 16 * nf + lg * 4 + i;
                float v = acc[of][nf][i] + bias;
                if (o < 128) Q [(size_t)(b * N_ + n) * CI_ + o]         = __float2bfloat16(v);
                else         Kb[(size_t)(b * N_ + n) * CI_ + (o - 128)] = __float2bfloat16(v);
            }
        }
    }
#pragma unroll
    for (int og = 0; og < 2; og++) {
#pragma unroll
        for (int i = 0; i < 4; i++) {
            int o = o0g + 16 * og + lg * 4 + i;
            float bias = Bg[o];
#pragma unroll
            for (int nf = 0; nf < 2; nf++) {
                int n = n0 + 16 * nf + lr;
                G[(size_t)(b * CI_ + o) * N_ + n] = __float2bfloat16(accg[og][nf][i] + bias);
            }
        }
    }
}

// ---------------- flash v8: K LDS dbuf; V direct from L2; LDS 24KB ---------
// grid: 32 qt * B_ * nchunk blocks of 256 (4 waves); wave = 32 q-rows, KVBLK=32.
__global__ __launch_bounds__(256, 3) void flash8(char* ws, int nchunk,
                                                 unsigned long long off_part,
                                                 unsigned long long off_ml) {
    const __hip_bfloat16* Q  = (const __hip_bfloat16*)(ws + OFF_Q);
    const __hip_bfloat16* Kb = (const __hip_bfloat16*)(ws + OFF_K);
    const __hip_bfloat16* G  = (const __hip_bfloat16*)(ws + OFF_G);
    __hip_bfloat16* OP = (__hip_bfloat16*)(ws + off_part);
    float* ML = (float*)(ws + off_ml);

    __shared__ char kbuf[2][32 * 256];   // K tile [32 j][256 B], key=(row&7)
    __shared__ char pbuf[4][2][1024];    // per-wave/per-qf P [16 q][64 B]

    int L = blockIdx.x;
    int npairs = B_ * nchunk;
    int pair = L % npairs, qt = L / npairs;
    int b = pair / nchunk, cz = pair % nchunk;
    int per = 128 / nchunk, rem = 128 % nchunk;
    int jb_t = per * cz + (cz < rem ? cz : rem);
    int sz_t = per + (cz < rem ? 1 : 0);
    int jb = jb_t << 5, je = jb + (sz_t << 5);

    int w = threadIdx.x >> 6, l = threadIdx.x & 63, lr = l & 15, lg = l >> 4;
    int q0 = qt * 128 + w * 32;
    int swz  = (lr & 7) << 4;          // K-row key (256B rows)
    int pswz = ((lr >> 1) & 3) << 4;   // P key (64B rows)
    char* pw = &pbuf[w][0][0];

    auto STAGE = [&](int pb_, int j0_) {
#pragma unroll
        for (int i = 0; i < 2; i++) {
            int row = w * 8 + i * 4 + (l >> 4);
            int bcol = ((l & 15) << 4) ^ ((row & 7) << 4);
            const char* src = (const char*)Kb + (((size_t)b * N_ + j0_ + row) << 8) + bcol;
            gload_lds16(src, &kbuf[pb_][(w * 8 + i * 4) * 256]);
        }
    };

    // Q as B-operand: lane holds Q[k = kk*32+lg*8+e][col q = q0+16qf+lr]
    s16x8 qa[2][4];
#pragma unroll
    for (int qf = 0; qf < 2; qf++) {
        const __hip_bfloat16* qrow = Q + ((size_t)b * N_ + q0 + 16 * qf + lr) * CI_ + lg * 8;
#pragma unroll
        for (int kk = 0; kk < 4; kk++) qa[qf][kk] = ld8(qrow + kk * 32);
    }

    f32x4 oacc[2][8] = {};
    float m_i[2], lsum[2] = {0.f, 0.f};

    STAGE(0, jb);
    __syncthreads();
    int pb = 0;

    for (int j0 = jb; j0 < je; j0 += 32) {
        // V prefetch: 8 independent L2 loads, issued first so latency hides
        // under QK + softmax (vmcnt wait at PV leaves next-K-stage in flight)
        s16x8 vreg[8];
#pragma unroll
        for (int cf = 0; cf < 8; cf++)
            vreg[cf] = ld8(G + ((size_t)b * CI_ + 16 * cf + lr) * N_ + j0 + lg * 8);
        if (j0 + 32 < je) STAGE(pb ^ 1, j0 + 32);
        const char* kb = kbuf[pb];
        // S^T = K Q  (swapped: lane owns 16 j of one q per qf)
        f32x4 s[2][2] = {};
        __builtin_amdgcn_s_setprio(1);
#pragma unroll
        for (int kk = 0; kk < 4; kk++) {
            int bc = ((kk << 6) + (lg << 4)) ^ swz;
            s16x8 kf0 = *(const s16x8*)(kb + lr * 256 + bc);
            s16x8 kf1 = *(const s16x8*)(kb + (16 + lr) * 256 + bc);
            s[0][0] = mfma16(kf0, qa[0][kk], s[0][0]);
            s[1][0] = mfma16(kf0, qa[1][kk], s[1][0]);
            s[0][1] = mfma16(kf1, qa[0][kk], s[0][1]);
            s[1][1] = mfma16(kf1, qa[1][kk], s[1][1]);
        }
        __builtin_amdgcn_s_setprio(0);
        // one-shot max init from first tile (per q row = lane lr, per qf)
        if (j0 == jb) {
#pragma unroll
            for (int qf = 0; qf < 2; qf++) {
                f32x4 m4;
                m4[0] = fmaxf(s[qf][0][0], s[qf][1][0]);
                m4[1] = fmaxf(s[qf][0][1], s[qf][1][1]);
                m4[2] = fmaxf(s[qf][0][2], s[qf][1][2]);
                m4[3] = fmaxf(s[qf][0][3], s[qf][1][3]);
                float tm = fmaxf(fmaxf(m4[0], m4[1]), fmaxf(m4[2], m4[3]));
                tm = fmaxf(tm, __shfl_xor(tm, 16));
                tm = fmaxf(tm, __shfl_xor(tm, 32));
                m_i[qf] = tm;
            }
        }
        // exp2 + lane-local l accumulation + pack P
#pragma unroll
        for (int qf = 0; qf < 2; qf++) {
            float mref = m_i[qf];
            f32x4 sum4 = {};
#pragma unroll
            for (int t = 0; t < 2; t++) {
#pragma unroll
                for (int i = 0; i < 4; i++) s[qf][t][i] = fexp2(s[qf][t][i] - mref);
                sum4 += s[qf][t];
            }
            lsum[qf] += (sum4[0] + sum4[1]) + (sum4[2] + sum4[3]);
            char* base = pw + qf * 1024 + lr * 64;
#pragma unroll
            for (int t = 0; t < 2; t++) {
                unsigned int lo = pk2(s[qf][t][0], s[qf][t][1]);
                unsigned int hi = pk2(s[qf][t][2], s[qf][t][3]);
                int slot = t * 2 + (lg >> 1);
                int byte0 = ((slot << 4) ^ pswz) + ((lg & 1) << 3);
                *(unsigned int*)(base + byte0)     = lo;
                *(unsigned int*)(base + byte0 + 4) = hi;
            }
        }
        s16x8 pa0 = *(const s16x8*)(pw + lr * 64 + ((lg << 4) ^ pswz));
        s16x8 pa1 = *(const s16x8*)(pw + 1024 + lr * 64 + ((lg << 4) ^ pswz));
        // PV from registers (V long since arrived)
        __builtin_amdgcn_s_setprio(1);
#pragma unroll
        for (int cf = 0; cf < 8; cf++) {
            oacc[0][cf] = mfma16(pa0, vreg[cf], oacc[0][cf]);
            oacc[1][cf] = mfma16(pa1, vreg[cf], oacc[1][cf]);
        }
        __builtin_amdgcn_s_setprio(0);
        __syncthreads();
        pb ^= 1;
    }
    // finalize l: 2 shuffles once per chunk
    float l_i[2];
#pragma unroll
    for (int qf = 0; qf < 2; qf++) {
        float rs = lsum[qf];
        rs += __shfl_xor(rs, 16);
        rs += __shfl_xor(rs, 32);
        l_i[qf] = rs;
    }
    // write unnormalized partial O + (m,l)
#pragma unroll
    for (int qf = 0; qf < 2; qf++) {
#pragma unroll
        for (int i = 0; i < 4; i++) {
            size_t row = ((size_t)(cz * B_ + b) * N_ + q0 + 16 * qf + lg * 4 + i) * CI_;
#pragma unroll
            for (int cf = 0; cf < 8; cf++)
                OP[row + 16 * cf + lr] = __float2bfloat16(oacc[qf][cf][i]);
        }
        if (lg == 0) {
            size_t mi = ((size_t)(cz * B_ + b) * N_ + q0 + 16 * qf + lr) * 2;
            ML[mi] = m_i[qf];
            ML[mi + 1] = l_i[qf];
        }
    }
}

// ------- fused epilogue: combine partials + out-proj + bias + residual -----
// grid (64, B_, 2), block 256; z splits the o-range (128 each)
template <int NC>
__global__ __launch_bounds__(256) void out_fused(const float* x, char* ws, float* y,
                                                 unsigned long long off_part,
                                                 unsigned long long off_ml) {
    const __hip_bfloat16* OP = (const __hip_bfloat16*)(ws + off_part);
    const float* ML = (const float*)(ws + off_ml);
    const __hip_bfloat16* Wo = (const __hip_bfloat16*)(ws + OFF_WOUT);
    const float* Bout = (const float*)(ws + OFF_BOUT);
    int b = blockIdx.y, oz = blockIdx.z;
    int w = threadIdx.x >> 6, l = threadIdx.x & 63, lr = l & 15, lg = l >> 4;
    int n0 = blockIdx.x * 64;
    // per-lane normalized combine weights for its 4 n rows
    float wz[4][NC];
#pragma unroll
    for (int nf = 0; nf < 4; nf++) {
        int n = n0 + 16 * nf + lr;
        float mz[NC], lz[NC], M = -1e30f;
#pragma unroll
        for (int z = 0; z < NC; z++) {
            size_t mi = ((size_t)(z * B_ + b) * N_ + n) * 2;
            mz[z] = ML[mi]; lz[z] = ML[mi + 1];
            M = fmaxf(M, mz[z]);
        }
        float Ls = 0.f;
#pragma unroll
        for (int z = 0; z < NC; z++) {
            float e = fexp2(mz[z] - M);
            wz[nf][z] = e;
            Ls += lz[z] * e;
        }
        float inv = 1.f / Ls;
#pragma unroll
        for (int z = 0; z < NC; z++) wz[nf][z] *= inv;
    }
    f32x4 acc[2][4] = {};   // [f2 o-tile][nf]
#pragma unroll
    for (int kk = 0; kk < 4; kk++) {
        s16x8 bb[4];
#pragma unroll
        for (int nf = 0; nf < 4; nf++) {
            int n = n0 + 16 * nf + lr;
            float o8[8] = {};
#pragma unroll
            for (int z = 0; z < NC; z++) {
                s16x8 v = ld8(OP + ((size_t)(z * B_ + b) * N_ + n) * CI_ + kk * 32 + lg * 8);
                float wv = wz[nf][z];
#pragma unroll
                for (int e = 0; e < 8; e++) o8[e] += wv * b2f(v[e]);
            }
            s16x8 r;
#pragma unroll
            for (int e = 0; e < 8; e++) {
                __hip_bfloat16 h = __float2bfloat16(o8[e]);
                r[e] = *(short*)&h;
            }
            bb[nf] = r;
        }
#pragma unroll
        for (int f2 = 0; f2 < 2; f2++) {
            s16x8 a = ld8(Wo + (size_t)(oz * 128 + w * 16 + f2 * 64 + lr) * CI_ + kk * 32 + lg * 8);
#pragma unroll
            for (int nf = 0; nf < 4; nf++)
                acc[f2][nf] = mfma16(a, bb[nf], acc[f2][nf]);
        }
    }
#pragma unroll
    for (int f2 = 0; f2 < 2; f2++) {
#pragma unroll
        for (int i = 0; i < 4; i++) {
            int o = oz * 128 + w * 16 + f2 * 64 + lg * 4 + i;
            float bias = Bout[o];
#pragma unroll
            for (int nf = 0; nf < 4; nf++) {
                int n = n0 + 16 * nf + lr;
                size_t idx = (size_t)(b * C_ + o) * N_ + n;
                y[idx] = acc[f2][nf][i] + bias + x[idx];
            }
        }
    }
}

extern "C" void kernel_launch(void* const* d_in, const int* in_sizes, int n_in,
                              void* d_out, int out_size, void* d_ws, size_t ws_size,
                              hipStream_t stream) {
    const float* x  = (const float*)d_in[0];
    const float* wg = (const float*)d_in[1];
    const float* bg = (const float*)d_in[2];
    const float* wt = (const float*)d_in[3];
    const float* bt = (const float*)d_in[4];
    const float* wp = (const float*)d_in[5];
    const float* bp = (const float*)d_in[6];
    const float* wo = (const float*)d_in[7];
    const float* bo = (const float*)d_in[8];
    char* ws = (char*)d_ws;
    float* y = (float*)d_out;

    // split-KV factor: 6 fills 256 CUs at 3 blocks/CU exactly (768 blocks)
    unsigned long long need6 = OFF_END + (24ull << 20) + (1ull << 20);
    unsigned long long need4 = OFF_END + (16ull << 20) + (1ull << 20);
    int nchunk;
    unsigned long long off_part, off_ml;
    if (ws_size >= need6) {
        nchunk = 6; off_part = OFF_END; off_ml = OFF_END + (24ull << 20);
    } else if (ws_size >= need4) {
        nchunk = 4; off_part = OFF_END; off_ml = OFF_END + (16ull << 20);
    } else {
        nchunk = 2; off_part = OFF_XT; off_ml = OFF_END;
    }

    prep_weights<<<256, 256, 0, stream>>>(wg, bg, wt, bt, wp, bp, wo, bo, ws);
    transpose_x<<<dim3(128, 8, 4), 256, 0, stream>>>(x, ws);
    proj<<<dim3(128, 4), 256, 0, stream>>>(ws);
    flash8<<<dim3(32 * B_ * nchunk), 256, 0, stream>>>(ws, nchunk, off_part, off_ml);
    if (nchunk == 6)
        out_fused<6><<<dim3(64, 4, 2), 256, 0, stream>>>(x, ws, y, off_part, off_ml);
    else if (nchunk == 4)
        out_fused<4><<<dim3(64, 4, 2), 256, 0, stream>>>(x, ws, y, off_part, off_ml);
    else
        out_fused<2><<<dim3(64, 4, 2), 256, 0, stream>>>(x, ws, y, off_part, off_ml);
}

// Round 9
// 103.766 us; speedup vs baseline: 1.5574x; 1.5574x over previous
//
#include <hip/hip_runtime.h>
#include <hip/hip_bf16.h>

// NonLocal block == flash attention (4 heads, N=4096, D=128) + 1x1-conv GEMMs.
// Round 9: attention on mfma_32x32x16 (2x flops per LDS byte); P stays fully
// in-register via pi-relabeled PV contraction (no P LDS, no shuffles); V read
// as 2x b64 at pi-slots (conflict-free). Epilogue = R6 combine + gemm_out.

typedef float f32x4 __attribute__((ext_vector_type(4)));
typedef float f32x16 __attribute__((ext_vector_type(16)));
typedef short s16x8 __attribute__((ext_vector_type(8)));
typedef short s16x4 __attribute__((ext_vector_type(4)));

#define B_  4
#define C_  256
#define CI_ 128
#define N_  4096

// workspace layout (bytes)
#define OFF_XT   0ull                    // bf16 [B][N][C]   8 MB
#define OFF_Q    (8ull  << 20)           // bf16 [B][N][CI]  4 MB (theta^T, scaled)
#define OFF_K    (12ull << 20)           // bf16 [B][N][CI]  4 MB (phi^T)
#define OFF_G    (16ull << 20)           // bf16 [B][CI][N]  4 MB (g, V^T layout)
#define OFF_O    (20ull << 20)           // bf16 [B][N][CI]  4 MB (combined attn out)
#define OFF_WQK  (24ull << 20)
#define OFF_WG   (OFF_WQK + 131072)
#define OFF_WOUT (OFF_WG  + 65536)
#define OFF_BQK  (OFF_WOUT + 65536)
#define OFF_BG   (OFF_BQK + 1024)
#define OFF_BOUT (OFF_BG  + 512)
#define OFF_END  (OFF_BOUT + 1024)       // = 25430528

__device__ inline f32x4 mfma16(s16x8 a, s16x8 b, f32x4 c) {
    return __builtin_amdgcn_mfma_f32_16x16x32_bf16(a, b, c, 0, 0, 0);
}
__device__ inline f32x16 mfma32(s16x8 a, s16x8 b, f32x16 c) {
    return __builtin_amdgcn_mfma_f32_32x32x16_bf16(a, b, c, 0, 0, 0);
}
__device__ inline s16x8 ld8(const __hip_bfloat16* p) { return *(const s16x8*)p; }
__device__ inline float b2f(short u) {
    return __uint_as_float(((unsigned int)(unsigned short)u) << 16);
}
__device__ inline unsigned int pk2(float a, float b) {
    __hip_bfloat162 h;
    h.x = __float2bfloat16(a); h.y = __float2bfloat16(b);
    return *(unsigned int*)&h;
}
__device__ inline void gload_lds16(const void* g, void* l) {
    __builtin_amdgcn_global_load_lds(
        (const __attribute__((address_space(1))) unsigned int*)g,
        (__attribute__((address_space(3))) unsigned int*)l, 16, 0, 0);
}
__device__ inline float fexp2(float x) { return __builtin_amdgcn_exp2f(x); }

// ---------------- weight prep: fp32 -> bf16; fold log2e/sqrt(Ci) into theta
__global__ void prep_weights(const float* wg, const float* bg,
                             const float* wt, const float* bt,
                             const float* wp, const float* bp,
                             const float* wo, const float* bo, char* ws) {
    __hip_bfloat16* Wqk  = (__hip_bfloat16*)(ws + OFF_WQK);
    __hip_bfloat16* Wg   = (__hip_bfloat16*)(ws + OFF_WG);
    __hip_bfloat16* Wout = (__hip_bfloat16*)(ws + OFF_WOUT);
    float* Bqk  = (float*)(ws + OFF_BQK);
    float* Bg   = (float*)(ws + OFF_BG);
    float* Bout = (float*)(ws + OFF_BOUT);
    const float rs = 0.08838834764831845f * 1.4426950408889634f;  // 1/sqrt(128)*log2(e)
    int idx = blockIdx.x * 256 + threadIdx.x;
    if (idx < 65536) {
        int r = idx >> 8, c = idx & 255;
        float v = (r < 128) ? wt[r * 256 + c] * rs : wp[(r - 128) * 256 + c];
        Wqk[idx] = __float2bfloat16(v);
    }
    if (idx < 32768) {
        Wg[idx]   = __float2bfloat16(wg[idx]);
        Wout[idx] = __float2bfloat16(wo[idx]);
    }
    if (idx < 256) { Bqk[idx] = (idx < 128) ? bt[idx] * rs : bp[idx - 128]; Bout[idx] = bo[idx]; }
    if (idx < 128) Bg[idx] = bg[idx];
}

// ---------------- x [B][C][N] f32 -> XT [B][N][C] bf16 -------------------
__global__ __launch_bounds__(256) void transpose_x(const float* x, char* ws) {
    __shared__ float tile[32][33];
    __hip_bfloat16* XT = (__hip_bfloat16*)(ws + OFF_XT);
    int b = blockIdx.z;
    int n0 = blockIdx.x * 32, c0 = blockIdx.y * 32;
    int tx = threadIdx.x & 31, ty = threadIdx.x >> 5;
#pragma unroll
    for (int r = 0; r < 4; r++)
        tile[ty + 8 * r][tx] = x[(size_t)(b * C_ + c0 + ty + 8 * r) * N_ + n0 + tx];
    __syncthreads();
#pragma unroll
    for (int r = 0; r < 4; r++)
        XT[(size_t)(b * N_ + n0 + ty + 8 * r) * C_ + c0 + tx] =
            __float2bfloat16(tile[tx][ty + 8 * r]);
}

// ---------------- fused projection: Q, K, G from XT in one pass ------------
__global__ __launch_bounds__(256) void proj(char* ws) {
    const __hip_bfloat16* XT  = (const __hip_bfloat16*)(ws + OFF_XT);
    const __hip_bfloat16* Wqk = (const __hip_bfloat16*)(ws + OFF_WQK);
    const __hip_bfloat16* Wg  = (const __hip_bfloat16*)(ws + OFF_WG);
    const float* Bqk = (const float*)(ws + OFF_BQK);
    const float* Bg  = (const float*)(ws + OFF_BG);
    __hip_bfloat16* Q  = (__hip_bfloat16*)(ws + OFF_Q);
    __hip_bfloat16* Kb = (__hip_bfloat16*)(ws + OFF_K);
    __hip_bfloat16* G  = (__hip_bfloat16*)(ws + OFF_G);

    __shared__ char at[32 * 512];   // [32 n][256 c] bf16, 16B slots XOR-swizzled

    int b = blockIdx.y, n0 = blockIdx.x * 32;
    int w = threadIdx.x >> 6, l = threadIdx.x & 63, lr = l & 15, lg = l >> 4;

    const char* xbase = (const char*)(XT + ((size_t)b * N_ + n0) * C_);
#pragma unroll
    for (int p = 0; p < 4; p++) {
        int row = p * 8 + w * 2 + (l >> 5);
        int slot = l & 31;
        const char* src = xbase + row * 512 + ((slot ^ (row & 7)) << 4);
        gload_lds16(src, &at[(p * 8 + w * 2) * 512]);
    }
    __syncthreads();

    f32x4 acc[4][2] = {};    // QK path: [of][nf]
    f32x4 accg[2][2] = {};   // G  path: [og][nf]
    int o0q = w * 64, o0g = w * 32;
#pragma unroll
    for (int kk = 0; kk < 8; kk++) {
        s16x8 a[2];
#pragma unroll
        for (int nf = 0; nf < 2; nf++) {
            int row = nf * 16 + lr;
            int s = (4 * kk + lg) ^ (row & 7);
            a[nf] = *(const s16x8*)(&at[row * 512 + s * 16]);
        }
#pragma unroll
        for (int of = 0; of < 4; of++) {
            s16x8 bb = ld8(Wqk + (size_t)(o0q + 16 * of + lr) * C_ + kk * 32 + lg * 8);
            acc[of][0] = mfma16(a[0], bb, acc[of][0]);
            acc[of][1] = mfma16(a[1], bb, acc[of][1]);
        }
#pragma unroll
        for (int og = 0; og < 2; og++) {
            s16x8 ag = ld8(Wg + (size_t)(o0g + 16 * og + lr) * C_ + kk * 32 + lg * 8);
            accg[og][0] = mfma16(ag, a[0], accg[og][0]);
            accg[og][1] = mfma16(ag, a[1], accg[og][1]);
        }
    }
#pragma unroll
    for (int of = 0; of < 4; of++) {
        int o = o0q + 16 * of + lr;
        float bias = Bqk[o];
#pragma unroll
        for (int nf = 0; nf < 2; nf++) {
#pragma unroll
            for (int i = 0; i < 4; i++) {
                int n = n0 + 16 * nf + lg * 4 + i;
                float v = acc[of][nf][i] + bias;
                if (o < 128) Q [(size_t)(b * N_ + n) * CI_ + o]         = __float2bfloat16(v);
                else         Kb[(size_t)(b * N_ + n) * CI_ + (o - 128)] = __float2bfloat16(v);
            }
        }
    }
#pragma unroll
    for (int og = 0; og < 2; og++) {
#pragma unroll
        for (int i = 0; i < 4; i++) {
            int o = o0g + 16 * og + lg * 4 + i;
            float bias = Bg[o];
#pragma unroll
            for (int nf = 0; nf < 2; nf++) {
                int n = n0 + 16 * nf + lr;
                G[(size_t)(b * CI_ + o) * N_ + n] = __float2bfloat16(accg[og][nf][i] + bias);
            }
        }
    }
}

// ---------------- flash v9: 32x32x16 MFMA, in-register P, K+V LDS dbuf -----
// grid: 32 qt * B_ * nchunk blocks of 256 (4 waves); wave = 32 q, KVBLK=32.
// PV uses pi-relabeled contraction pi(k)=(k&3)+8*(k>>2)+4*(k>>3): A-frag is
// the QK D-regs packed in order; V supplied as 2x b64 at matching slots.
__global__ __launch_bounds__(256, 3) void flash9(char* ws, int nchunk,
                                                 unsigned long long off_part,
                                                 unsigned long long off_ml) {
    const __hip_bfloat16* Q  = (const __hip_bfloat16*)(ws + OFF_Q);
    const __hip_bfloat16* Kb = (const __hip_bfloat16*)(ws + OFF_K);
    const __hip_bfloat16* G  = (const __hip_bfloat16*)(ws + OFF_G);
    __hip_bfloat16* OP = (__hip_bfloat16*)(ws + off_part);
    float* ML = (float*)(ws + off_ml);

    __shared__ char kbuf[2][32 * 256];   // K tile [32 j][256 B], slot key (row&7)
    __shared__ char vbuf[2][128 * 64];   // V tile [128 c][64 B], slot key ((c>>1)&3)

    int L = blockIdx.x;
    int npairs = B_ * nchunk;
    int pair = L % npairs, qt = L / npairs;
    int b = pair / nchunk, cz = pair % nchunk;
    int per = 128 / nchunk, rem = 128 % nchunk;
    int jb_t = per * cz + (cz < rem ? cz : rem);
    int sz_t = per + (cz < rem ? 1 : 0);
    int jb = jb_t << 5, je = jb + (sz_t << 5);

    int w = threadIdx.x >> 6, l = threadIdx.x & 63;
    int cl = l & 31, hi = l >> 5;
    int q0 = qt * 128 + w * 32;
    int kkey = (l & 7) << 4;        // K slot key (row = cl)
    int vkey = (l >> 1) & 3;        // V slot key (row c = cb*32+cl)

    auto STAGE = [&](int pb_, int j0_) {
#pragma unroll
        for (int i = 0; i < 2; i++) {
            int row = w * 8 + i * 4 + (l >> 4);
            int bcol = ((l & 15) << 4) ^ ((row & 7) << 4);
            const char* src = (const char*)Kb + (((size_t)b * N_ + j0_ + row) << 8) + bcol;
            gload_lds16(src, &kbuf[pb_][(w * 8 + i * 4) * 256]);
        }
#pragma unroll
        for (int i = 0; i < 2; i++) {
            int c = w * 32 + i * 16 + (l >> 2);
            int srcslot = (l & 3) ^ ((l >> 3) & 3);
            const char* src = (const char*)G + ((((size_t)b * CI_ + c) * N_ + j0_) << 1)
                              + (srcslot << 4);
            gload_lds16(src, &vbuf[pb_][(w * 32 + i * 16) * 64]);
        }
    };

    // Q as B-operand (32x32x16): lane holds Q[k = st*16 + hi*8 + e][q = q0+cl]
    s16x8 qb[8];
    {
        const __hip_bfloat16* qrow = Q + ((size_t)b * N_ + q0 + cl) * CI_ + hi * 8;
#pragma unroll
        for (int st = 0; st < 8; st++) qb[st] = ld8(qrow + st * 16);
    }

    f32x16 oacc[4] = {};
    float m_i = 0.f, lsum = 0.f;

    STAGE(0, jb);
    __syncthreads();
    int pb = 0;

    for (int j0 = jb; j0 < je; j0 += 32) {
        if (j0 + 32 < je) STAGE(pb ^ 1, j0 + 32);
        const char* kb = kbuf[pb];
        const char* vbb = vbuf[pb];
        // S^T[j][q] = K Q : A = K[32j][16k] from LDS, B = Q regs
        f32x16 s = {};
        __builtin_amdgcn_s_setprio(1);
#pragma unroll
        for (int st = 0; st < 8; st++) {
            s16x8 kf = *(const s16x8*)(kb + cl * 256 + ((((st << 1) + hi) << 4) ^ kkey));
            s = mfma32(kf, qb[st], s);
        }
        __builtin_amdgcn_s_setprio(0);
        // one-shot max from first tile (lane owns 16 j's of q=cl; partner has rest)
        if (j0 == jb) {
            float t0 = fmaxf(fmaxf(s[0], s[1]), fmaxf(s[2], s[3]));
            float t1 = fmaxf(fmaxf(s[4], s[5]), fmaxf(s[6], s[7]));
            float t2 = fmaxf(fmaxf(s[8], s[9]), fmaxf(s[10], s[11]));
            float t3 = fmaxf(fmaxf(s[12], s[13]), fmaxf(s[14], s[15]));
            float tm = fmaxf(fmaxf(t0, t1), fmaxf(t2, t3));
            tm = fmaxf(tm, __shfl_xor(tm, 32));
            m_i = tm;
        }
        // exp2 + lane-local l accumulation
#pragma unroll
        for (int r = 0; r < 16; r++) s[r] = fexp2(s[r] - m_i);
        lsum += ((s[0] + s[1]) + (s[2] + s[3])) + ((s[4] + s[5]) + (s[6] + s[7]))
              + ((s[8] + s[9]) + (s[10] + s[11])) + ((s[12] + s[13]) + (s[14] + s[15]));
        // pack P into A-frags: pi-order == D-reg order, no cross-lane moves
        union { unsigned int u[4]; s16x8 v; } pa0, pa1;
#pragma unroll
        for (int i = 0; i < 4; i++) {
            pa0.u[i] = pk2(s[2 * i], s[2 * i + 1]);
            pa1.u[i] = pk2(s[8 + 2 * i], s[9 + 2 * i]);
        }
        // PV: O[q][c] += P V ; V B-frag elem e: j = u*16 + (e&3) + 8*(e>>2) + 4*hi
        __builtin_amdgcn_s_setprio(1);
#pragma unroll
        for (int u = 0; u < 2; u++) {
            s16x8 pa = u ? pa1.v : pa0.v;
#pragma unroll
            for (int cb = 0; cb < 4; cb++) {
                const char* base = vbb + ((cb * 32 + cl) << 6) + hi * 8;
                union { s16x4 h[2]; s16x8 v; } vf;
                vf.h[0] = *(const s16x4*)(base + ((((u << 1))     ^ vkey) << 4));
                vf.h[1] = *(const s16x4*)(base + ((((u << 1) | 1) ^ vkey) << 4));
                oacc[cb] = mfma32(pa, vf.v, oacc[cb]);
            }
        }
        __builtin_amdgcn_s_setprio(0);
        __syncthreads();
        pb ^= 1;
    }
    lsum += __shfl_xor(lsum, 32);
    // write unnormalized partial O + (m,l)
#pragma unroll
    for (int cb = 0; cb < 4; cb++) {
#pragma unroll
        for (int r = 0; r < 16; r++) {
            int q = q0 + (r & 3) + 8 * (r >> 2) + 4 * hi;
            OP[((size_t)(cz * B_ + b) * N_ + q) * CI_ + cb * 32 + cl] =
                __float2bfloat16(oacc[cb][r]);
        }
    }
    if (l < 32) {
        size_t mi = ((size_t)(cz * B_ + b) * N_ + q0 + l) * 2;
        ML[mi] = m_i;
        ML[mi + 1] = lsum;
    }
}

// ---------------- combine split-KV partials -> O ---------------------------
template <int NC>
__global__ __launch_bounds__(256) void combine(char* ws,
                                               unsigned long long off_part,
                                               unsigned long long off_ml) {
    const __hip_bfloat16* OP = (const __hip_bfloat16*)(ws + off_part);
    const float* ML = (const float*)(ws + off_ml);
    __hip_bfloat16* O = (__hip_bfloat16*)(ws + OFF_O);
    int idx = blockIdx.x * 256 + threadIdx.x;      // B*N*16 threads
    int cg = idx & 15, n = (idx >> 4) & (N_ - 1), b = idx >> 16;
    float mz[NC], lz[NC], M = -1e30f;
#pragma unroll
    for (int z = 0; z < NC; z++) {
        size_t mi = ((size_t)(z * B_ + b) * N_ + n) * 2;
        mz[z] = ML[mi]; lz[z] = ML[mi + 1];
        M = fmaxf(M, mz[z]);
    }
    float Lsum = 0.f, wz[NC];
#pragma unroll
    for (int z = 0; z < NC; z++) { wz[z] = fexp2(mz[z] - M); Lsum += lz[z] * wz[z]; }
    float inv = 1.f / Lsum;
    float o[8] = {};
#pragma unroll
    for (int z = 0; z < NC; z++) {
        s16x8 v = ld8(OP + ((size_t)(z * B_ + b) * N_ + n) * CI_ + cg * 8);
        float wv = wz[z] * inv;
#pragma unroll
        for (int i = 0; i < 8; i++) o[i] += wv * b2f(v[i]);
    }
    s16x8 r;
#pragma unroll
    for (int i = 0; i < 8; i++) {
        __hip_bfloat16 h = __float2bfloat16(o[i]);
        r[i] = *(short*)&h;
    }
    *(s16x8*)(O + ((size_t)b * N_ + n) * CI_ + cg * 8) = r;
}

// ---------------- out projection + bias + residual (single pass over O) ----
__global__ __launch_bounds__(256) void gemm_out(const float* x, char* ws, float* y) {
    const __hip_bfloat16* Ob = (const __hip_bfloat16*)(ws + OFF_O);
    const __hip_bfloat16* Wo = (const __hip_bfloat16*)(ws + OFF_WOUT);
    const float* Bout = (const float*)(ws + OFF_BOUT);
    int b = blockIdx.y;
    int w = threadIdx.x >> 6, l = threadIdx.x & 63, lr = l & 15, lg = l >> 4;
    int n0 = blockIdx.x * 64;
    f32x4 acc[4][4] = {};   // [f2 o-tile][nf]
#pragma unroll
    for (int kk = 0; kk < 4; kk++) {
        s16x8 bb[4];
#pragma unroll
        for (int nf = 0; nf < 4; nf++)
            bb[nf] = ld8(Ob + (size_t)(b * N_ + n0 + 16 * nf + lr) * CI_ + kk * 32 + lg * 8);
#pragma unroll
        for (int f2 = 0; f2 < 4; f2++) {
            s16x8 a = ld8(Wo + (size_t)(w * 16 + f2 * 64 + lr) * CI_ + kk * 32 + lg * 8);
#pragma unroll
            for (int nf = 0; nf < 4; nf++)
                acc[f2][nf] = mfma16(a, bb[nf], acc[f2][nf]);
        }
    }
#pragma unroll
    for (int f2 = 0; f2 < 4; f2++) {
#pragma unroll
        for (int i = 0; i < 4; i++) {
            int o = w * 16 + f2 * 64 + lg * 4 + i;
            float bias = Bout[o];
#pragma unroll
            for (int nf = 0; nf < 4; nf++) {
                int n = n0 + 16 * nf + lr;
                size_t idx = (size_t)(b * C_ + o) * N_ + n;
                y[idx] = acc[f2][nf][i] + bias + x[idx];
            }
        }
    }
}

extern "C" void kernel_launch(void* const* d_in, const int* in_sizes, int n_in,
                              void* d_out, int out_size, void* d_ws, size_t ws_size,
                              hipStream_t stream) {
    const float* x  = (const float*)d_in[0];
    const float* wg = (const float*)d_in[1];
    const float* bg = (const float*)d_in[2];
    const float* wt = (const float*)d_in[3];
    const float* bt = (const float*)d_in[4];
    const float* wp = (const float*)d_in[5];
    const float* bp = (const float*)d_in[6];
    const float* wo = (const float*)d_in[7];
    const float* bo = (const float*)d_in[8];
    char* ws = (char*)d_ws;
    float* y = (float*)d_out;

    // split-KV factor: 6 fills 256 CUs at 3 blocks/CU exactly (768 blocks)
    unsigned long long need6 = OFF_END + (24ull << 20) + (1ull << 20);
    unsigned long long need4 = OFF_END + (16ull << 20) + (1ull << 20);
    int nchunk;
    unsigned long long off_part, off_ml;
    if (ws_size >= need6) {
        nchunk = 6; off_part = OFF_END; off_ml = OFF_END + (24ull << 20);
    } else if (ws_size >= need4) {
        nchunk = 4; off_part = OFF_END; off_ml = OFF_END + (16ull << 20);
    } else {
        nchunk = 2; off_part = OFF_XT; off_ml = OFF_END;
    }

    prep_weights<<<256, 256, 0, stream>>>(wg, bg, wt, bt, wp, bp, wo, bo, ws);
    transpose_x<<<dim3(128, 8, 4), 256, 0, stream>>>(x, ws);
    proj<<<dim3(128, 4), 256, 0, stream>>>(ws);
    flash9<<<dim3(32 * B_ * nchunk), 256, 0, stream>>>(ws, nchunk, off_part, off_ml);
    if (nchunk == 6)      combine<6><<<1024, 256, 0, stream>>>(ws, off_part, off_ml);
    else if (nchunk == 4) combine<4><<<1024, 256, 0, stream>>>(ws, off_part, off_ml);
    else                  combine<2><<<1024, 256, 0, stream>>>(ws, off_part, off_ml);
    gemm_out<<<dim3(64, 4), 256, 0, stream>>>(x, ws, y);
}

// Round 10
// 98.333 us; speedup vs baseline: 1.6434x; 1.0553x over previous
//
#include <hip/hip_runtime.h>
#include <hip/hip_bf16.h>

// NonLocal block == flash attention (4 heads, N=4096, D=128) + 1x1-conv GEMMs.
// Round 10: transpose fused into proj (x read once, XT buffer + kernel gone);
// gemm_out re-gridded to 512 blocks (2/CU). flash9/combine/prep frozen.

typedef float f32x4 __attribute__((ext_vector_type(4)));
typedef float f32x16 __attribute__((ext_vector_type(16)));
typedef short s16x8 __attribute__((ext_vector_type(8)));
typedef short s16x4 __attribute__((ext_vector_type(4)));

#define B_  4
#define C_  256
#define CI_ 128
#define N_  4096

// workspace layout (bytes)
#define OFF_Q    (8ull  << 20)           // bf16 [B][N][CI]  4 MB (theta^T, scaled)
#define OFF_K    (12ull << 20)           // bf16 [B][N][CI]  4 MB (phi^T)
#define OFF_G    (16ull << 20)           // bf16 [B][CI][N]  4 MB (g, V^T layout)
#define OFF_O    (20ull << 20)           // bf16 [B][N][CI]  4 MB (combined attn out)
#define OFF_WQK  (24ull << 20)
#define OFF_WG   (OFF_WQK + 131072)
#define OFF_WOUT (OFF_WG  + 65536)
#define OFF_BQK  (OFF_WOUT + 65536)
#define OFF_BG   (OFF_BQK + 1024)
#define OFF_BOUT (OFF_BG  + 512)
#define OFF_END  (OFF_BOUT + 1024)       // = 25430528

__device__ inline f32x4 mfma16(s16x8 a, s16x8 b, f32x4 c) {
    return __builtin_amdgcn_mfma_f32_16x16x32_bf16(a, b, c, 0, 0, 0);
}
__device__ inline f32x16 mfma32(s16x8 a, s16x8 b, f32x16 c) {
    return __builtin_amdgcn_mfma_f32_32x32x16_bf16(a, b, c, 0, 0, 0);
}
__device__ inline s16x8 ld8(const __hip_bfloat16* p) { return *(const s16x8*)p; }
__device__ inline float b2f(short u) {
    return __uint_as_float(((unsigned int)(unsigned short)u) << 16);
}
__device__ inline unsigned int pk2(float a, float b) {
    __hip_bfloat162 h;
    h.x = __float2bfloat16(a); h.y = __float2bfloat16(b);
    return *(unsigned int*)&h;
}
__device__ inline void gload_lds16(const void* g, void* l) {
    __builtin_amdgcn_global_load_lds(
        (const __attribute__((address_space(1))) unsigned int*)g,
        (__attribute__((address_space(3))) unsigned int*)l, 16, 0, 0);
}
__device__ inline float fexp2(float x) { return __builtin_amdgcn_exp2f(x); }

// ---------------- weight prep: fp32 -> bf16; fold log2e/sqrt(Ci) into theta
__global__ void prep_weights(const float* wg, const float* bg,
                             const float* wt, const float* bt,
                             const float* wp, const float* bp,
                             const float* wo, const float* bo, char* ws) {
    __hip_bfloat16* Wqk  = (__hip_bfloat16*)(ws + OFF_WQK);
    __hip_bfloat16* Wg   = (__hip_bfloat16*)(ws + OFF_WG);
    __hip_bfloat16* Wout = (__hip_bfloat16*)(ws + OFF_WOUT);
    float* Bqk  = (float*)(ws + OFF_BQK);
    float* Bg   = (float*)(ws + OFF_BG);
    float* Bout = (float*)(ws + OFF_BOUT);
    const float rs = 0.08838834764831845f * 1.4426950408889634f;  // 1/sqrt(128)*log2(e)
    int idx = blockIdx.x * 256 + threadIdx.x;
    if (idx < 65536) {
        int r = idx >> 8, c = idx & 255;
        float v = (r < 128) ? wt[r * 256 + c] * rs : wp[(r - 128) * 256 + c];
        Wqk[idx] = __float2bfloat16(v);
    }
    if (idx < 32768) {
        Wg[idx]   = __float2bfloat16(wg[idx]);
        Wout[idx] = __float2bfloat16(wo[idx]);
    }
    if (idx < 256) { Bqk[idx] = (idx < 128) ? bt[idx] * rs : bp[idx - 128]; Bout[idx] = bo[idx]; }
    if (idx < 128) Bg[idx] = bg[idx];
}

// ---------------- fused transpose + projection: Q, K, G from x in one pass -
// grid (128, B_), block 256 (4 waves). Stage x[b][:, n0..n0+32] transposed
// into at[32 n][256 c] bf16 (16B-slot XOR swizzle) via reg staging, then the
// same dual-use MFMA pass as before.
__global__ __launch_bounds__(256) void proj(const float* x, char* ws) {
    const __hip_bfloat16* Wqk = (const __hip_bfloat16*)(ws + OFF_WQK);
    const __hip_bfloat16* Wg  = (const __hip_bfloat16*)(ws + OFF_WG);
    const float* Bqk = (const float*)(ws + OFF_BQK);
    const float* Bg  = (const float*)(ws + OFF_BG);
    __hip_bfloat16* Q  = (__hip_bfloat16*)(ws + OFF_Q);
    __hip_bfloat16* Kb = (__hip_bfloat16*)(ws + OFF_K);
    __hip_bfloat16* G  = (__hip_bfloat16*)(ws + OFF_G);

    __shared__ char at[32 * 512];   // [32 n][256 c] bf16, 16B slots XOR-swizzled

    int b = blockIdx.y, n0 = blockIdx.x * 32;
    int t = threadIdx.x;
    int w = t >> 6, l = t & 63, lr = l & 15, lg = l >> 4;

    // transpose-stage: thread t handles c = p*8 + (t>>5), n = t&31
    {
        int cb8 = t >> 5;          // 0..7
        int n = t & 31;
        const float* xcol = x + ((size_t)b * C_) * N_ + n0 + n;
#pragma unroll
        for (int p = 0; p < 32; p++) {
            int c = p * 8 + cb8;
            float v = xcol[(size_t)c * N_];
            int byte0 = n * 512 + ((((c >> 3) ^ (n & 7)) << 4) | ((c & 7) << 1));
            *(unsigned short*)(&at[byte0]) = (unsigned short)(
                *(unsigned int*)&v >> 16) + ((*(unsigned int*)&v >> 15) & 1);
        }
    }
    __syncthreads();

    f32x4 acc[4][2] = {};    // QK path: [of][nf]
    f32x4 accg[2][2] = {};   // G  path: [og][nf]
    int o0q = w * 64, o0g = w * 32;
#pragma unroll
    for (int kk = 0; kk < 8; kk++) {
        s16x8 a[2];
#pragma unroll
        for (int nf = 0; nf < 2; nf++) {
            int row = nf * 16 + lr;
            int s = (4 * kk + lg) ^ (row & 7);
            a[nf] = *(const s16x8*)(&at[row * 512 + s * 16]);
        }
#pragma unroll
        for (int of = 0; of < 4; of++) {
            s16x8 bb = ld8(Wqk + (size_t)(o0q + 16 * of + lr) * C_ + kk * 32 + lg * 8);
            acc[of][0] = mfma16(a[0], bb, acc[of][0]);
            acc[of][1] = mfma16(a[1], bb, acc[of][1]);
        }
#pragma unroll
        for (int og = 0; og < 2; og++) {
            s16x8 ag = ld8(Wg + (size_t)(o0g + 16 * og + lr) * C_ + kk * 32 + lg * 8);
            accg[og][0] = mfma16(ag, a[0], accg[og][0]);
            accg[og][1] = mfma16(ag, a[1], accg[og][1]);
        }
    }
#pragma unroll
    for (int of = 0; of < 4; of++) {
        int o = o0q + 16 * of + lr;
        float bias = Bqk[o];
#pragma unroll
        for (int nf = 0; nf < 2; nf++) {
#pragma unroll
            for (int i = 0; i < 4; i++) {
                int n = n0 + 16 * nf + lg * 4 + i;
                float v = acc[of][nf][i] + bias;
                if (o < 128) Q [(size_t)(b * N_ + n) * CI_ + o]         = __float2bfloat16(v);
                else         Kb[(size_t)(b * N_ + n) * CI_ + (o - 128)] = __float2bfloat16(v);
            }
        }
    }
#pragma unroll
    for (int og = 0; og < 2; og++) {
#pragma unroll
        for (int i = 0; i < 4; i++) {
            int o = o0g + 16 * og + lg * 4 + i;
            float bias = Bg[o];
#pragma unroll
            for (int nf = 0; nf < 2; nf++) {
                int n = n0 + 16 * nf + lr;
                G[(size_t)(b * CI_ + o) * N_ + n] = __float2bfloat16(accg[og][nf][i] + bias);
            }
        }
    }
}

// ---------------- flash v9: 32x32x16 MFMA, in-register P, K+V LDS dbuf -----
// (frozen from R9)
__global__ __launch_bounds__(256, 3) void flash9(char* ws, int nchunk,
                                                 unsigned long long off_part,
                                                 unsigned long long off_ml) {
    const __hip_bfloat16* Q  = (const __hip_bfloat16*)(ws + OFF_Q);
    const __hip_bfloat16* Kb = (const __hip_bfloat16*)(ws + OFF_K);
    const __hip_bfloat16* G  = (const __hip_bfloat16*)(ws + OFF_G);
    __hip_bfloat16* OP = (__hip_bfloat16*)(ws + off_part);
    float* ML = (float*)(ws + off_ml);

    __shared__ char kbuf[2][32 * 256];   // K tile [32 j][256 B], slot key (row&7)
    __shared__ char vbuf[2][128 * 64];   // V tile [128 c][64 B], slot key ((c>>1)&3)

    int L = blockIdx.x;
    int npairs = B_ * nchunk;
    int pair = L % npairs, qt = L / npairs;
    int b = pair / nchunk, cz = pair % nchunk;
    int per = 128 / nchunk, rem = 128 % nchunk;
    int jb_t = per * cz + (cz < rem ? cz : rem);
    int sz_t = per + (cz < rem ? 1 : 0);
    int jb = jb_t << 5, je = jb + (sz_t << 5);

    int w = threadIdx.x >> 6, l = threadIdx.x & 63;
    int cl = l & 31, hi = l >> 5;
    int q0 = qt * 128 + w * 32;
    int kkey = (l & 7) << 4;        // K slot key (row = cl)
    int vkey = (l >> 1) & 3;        // V slot key (row c = cb*32+cl)

    auto STAGE = [&](int pb_, int j0_) {
#pragma unroll
        for (int i = 0; i < 2; i++) {
            int row = w * 8 + i * 4 + (l >> 4);
            int bcol = ((l & 15) << 4) ^ ((row & 7) << 4);
            const char* src = (const char*)Kb + (((size_t)b * N_ + j0_ + row) << 8) + bcol;
            gload_lds16(src, &kbuf[pb_][(w * 8 + i * 4) * 256]);
        }
#pragma unroll
        for (int i = 0; i < 2; i++) {
            int c = w * 32 + i * 16 + (l >> 2);
            int srcslot = (l & 3) ^ ((l >> 3) & 3);
            const char* src = (const char*)G + ((((size_t)b * CI_ + c) * N_ + j0_) << 1)
                              + (srcslot << 4);
            gload_lds16(src, &vbuf[pb_][(w * 32 + i * 16) * 64]);
        }
    };

    s16x8 qb[8];
    {
        const __hip_bfloat16* qrow = Q + ((size_t)b * N_ + q0 + cl) * CI_ + hi * 8;
#pragma unroll
        for (int st = 0; st < 8; st++) qb[st] = ld8(qrow + st * 16);
    }

    f32x16 oacc[4] = {};
    float m_i = 0.f, lsum = 0.f;

    STAGE(0, jb);
    __syncthreads();
    int pb = 0;

    for (int j0 = jb; j0 < je; j0 += 32) {
        if (j0 + 32 < je) STAGE(pb ^ 1, j0 + 32);
        const char* kb = kbuf[pb];
        const char* vbb = vbuf[pb];
        f32x16 s = {};
        __builtin_amdgcn_s_setprio(1);
#pragma unroll
        for (int st = 0; st < 8; st++) {
            s16x8 kf = *(const s16x8*)(kb + cl * 256 + ((((st << 1) + hi) << 4) ^ kkey));
            s = mfma32(kf, qb[st], s);
        }
        __builtin_amdgcn_s_setprio(0);
        if (j0 == jb) {
            float t0 = fmaxf(fmaxf(s[0], s[1]), fmaxf(s[2], s[3]));
            float t1 = fmaxf(fmaxf(s[4], s[5]), fmaxf(s[6], s[7]));
            float t2 = fmaxf(fmaxf(s[8], s[9]), fmaxf(s[10], s[11]));
            float t3 = fmaxf(fmaxf(s[12], s[13]), fmaxf(s[14], s[15]));
            float tm = fmaxf(fmaxf(t0, t1), fmaxf(t2, t3));
            tm = fmaxf(tm, __shfl_xor(tm, 32));
            m_i = tm;
        }
#pragma unroll
        for (int r = 0; r < 16; r++) s[r] = fexp2(s[r] - m_i);
        lsum += ((s[0] + s[1]) + (s[2] + s[3])) + ((s[4] + s[5]) + (s[6] + s[7]))
              + ((s[8] + s[9]) + (s[10] + s[11])) + ((s[12] + s[13]) + (s[14] + s[15]));
        union { unsigned int u[4]; s16x8 v; } pa0, pa1;
#pragma unroll
        for (int i = 0; i < 4; i++) {
            pa0.u[i] = pk2(s[2 * i], s[2 * i + 1]);
            pa1.u[i] = pk2(s[8 + 2 * i], s[9 + 2 * i]);
        }
        __builtin_amdgcn_s_setprio(1);
#pragma unroll
        for (int u = 0; u < 2; u++) {
            s16x8 pa = u ? pa1.v : pa0.v;
#pragma unroll
            for (int cb = 0; cb < 4; cb++) {
                const char* base = vbb + ((cb * 32 + cl) << 6) + hi * 8;
                union { s16x4 h[2]; s16x8 v; } vf;
                vf.h[0] = *(const s16x4*)(base + ((((u << 1))     ^ vkey) << 4));
                vf.h[1] = *(const s16x4*)(base + ((((u << 1) | 1) ^ vkey) << 4));
                oacc[cb] = mfma32(pa, vf.v, oacc[cb]);
            }
        }
        __builtin_amdgcn_s_setprio(0);
        __syncthreads();
        pb ^= 1;
    }
    lsum += __shfl_xor(lsum, 32);
#pragma unroll
    for (int cb = 0; cb < 4; cb++) {
#pragma unroll
        for (int r = 0; r < 16; r++) {
            int q = q0 + (r & 3) + 8 * (r >> 2) + 4 * hi;
            OP[((size_t)(cz * B_ + b) * N_ + q) * CI_ + cb * 32 + cl] =
                __float2bfloat16(oacc[cb][r]);
        }
    }
    if (l < 32) {
        size_t mi = ((size_t)(cz * B_ + b) * N_ + q0 + l) * 2;
        ML[mi] = m_i;
        ML[mi + 1] = lsum;
    }
}

// ---------------- combine split-KV partials -> O (frozen) ------------------
template <int NC>
__global__ __launch_bounds__(256) void combine(char* ws,
                                               unsigned long long off_part,
                                               unsigned long long off_ml) {
    const __hip_bfloat16* OP = (const __hip_bfloat16*)(ws + off_part);
    const float* ML = (const float*)(ws + off_ml);
    __hip_bfloat16* O = (__hip_bfloat16*)(ws + OFF_O);
    int idx = blockIdx.x * 256 + threadIdx.x;      // B*N*16 threads
    int cg = idx & 15, n = (idx >> 4) & (N_ - 1), b = idx >> 16;
    float mz[NC], lz[NC], M = -1e30f;
#pragma unroll
    for (int z = 0; z < NC; z++) {
        size_t mi = ((size_t)(z * B_ + b) * N_ + n) * 2;
        mz[z] = ML[mi]; lz[z] = ML[mi + 1];
        M = fmaxf(M, mz[z]);
    }
    float Lsum = 0.f, wz[NC];
#pragma unroll
    for (int z = 0; z < NC; z++) { wz[z] = fexp2(mz[z] - M); Lsum += lz[z] * wz[z]; }
    float inv = 1.f / Lsum;
    float o[8] = {};
#pragma unroll
    for (int z = 0; z < NC; z++) {
        s16x8 v = ld8(OP + ((size_t)(z * B_ + b) * N_ + n) * CI_ + cg * 8);
        float wv = wz[z] * inv;
#pragma unroll
        for (int i = 0; i < 8; i++) o[i] += wv * b2f(v[i]);
    }
    s16x8 r;
#pragma unroll
    for (int i = 0; i < 8; i++) {
        __hip_bfloat16 h = __float2bfloat16(o[i]);
        r[i] = *(short*)&h;
    }
    *(s16x8*)(O + ((size_t)b * N_ + n) * CI_ + cg * 8) = r;
}

// ---------------- out projection + bias + residual -------------------------
// grid (128, B_) = 512 blocks (2/CU); wave = 64 o x 32 n
__global__ __launch_bounds__(256) void gemm_out(const float* x, char* ws, float* y) {
    const __hip_bfloat16* Ob = (const __hip_bfloat16*)(ws + OFF_O);
    const __hip_bfloat16* Wo = (const __hip_bfloat16*)(ws + OFF_WOUT);
    const float* Bout = (const float*)(ws + OFF_BOUT);
    int b = blockIdx.y;
    int w = threadIdx.x >> 6, l = threadIdx.x & 63, lr = l & 15, lg = l >> 4;
    int n0 = blockIdx.x * 32;
    int o0 = w * 64;
    f32x4 acc[4][2] = {};   // [of][nf]
#pragma unroll
    for (int kk = 0; kk < 4; kk++) {
        s16x8 bb[2];
#pragma unroll
        for (int nf = 0; nf < 2; nf++)
            bb[nf] = ld8(Ob + (size_t)(b * N_ + n0 + 16 * nf + lr) * CI_ + kk * 32 + lg * 8);
#pragma unroll
        for (int of = 0; of < 4; of++) {
            s16x8 a = ld8(Wo + (size_t)(o0 + 16 * of + lr) * CI_ + kk * 32 + lg * 8);
#pragma unroll
            for (int nf = 0; nf < 2; nf++)
                acc[of][nf] = mfma16(a, bb[nf], acc[of][nf]);
        }
    }
#pragma unroll
    for (int of = 0; of < 4; of++) {
#pragma unroll
        for (int i = 0; i < 4; i++) {
            int o = o0 + 16 * of + lg * 4 + i;
            float bias = Bout[o];
#pragma unroll
            for (int nf = 0; nf < 2; nf++) {
                int n = n0 + 16 * nf + lr;
                size_t idx = (size_t)(b * C_ + o) * N_ + n;
                y[idx] = acc[of][nf][i] + bias + x[idx];
            }
        }
    }
}

extern "C" void kernel_launch(void* const* d_in, const int* in_sizes, int n_in,
                              void* d_out, int out_size, void* d_ws, size_t ws_size,
                              hipStream_t stream) {
    const float* x  = (const float*)d_in[0];
    const float* wg = (const float*)d_in[1];
    const float* bg = (const float*)d_in[2];
    const float* wt = (const float*)d_in[3];
    const float* bt = (const float*)d_in[4];
    const float* wp = (const float*)d_in[5];
    const float* bp = (const float*)d_in[6];
    const float* wo = (const float*)d_in[7];
    const float* bo = (const float*)d_in[8];
    char* ws = (char*)d_ws;
    float* y = (float*)d_out;

    // split-KV factor: 6 fills 256 CUs at 3 blocks/CU exactly (768 blocks)
    unsigned long long need6 = OFF_END + (24ull << 20) + (1ull << 20);
    unsigned long long need4 = OFF_END + (16ull << 20) + (1ull << 20);
    int nchunk;
    unsigned long long off_part, off_ml;
    if (ws_size >= need6) {
        nchunk = 6; off_part = OFF_END; off_ml = OFF_END + (24ull << 20);
    } else if (ws_size >= need4) {
        nchunk = 4; off_part = OFF_END; off_ml = OFF_END + (16ull << 20);
    } else {
        nchunk = 2; off_part = 0ull; off_ml = OFF_END;   // partials in dead low region
    }

    prep_weights<<<256, 256, 0, stream>>>(wg, bg, wt, bt, wp, bp, wo, bo, ws);
    proj<<<dim3(128, 4), 256, 0, stream>>>(x, ws);
    flash9<<<dim3(32 * B_ * nchunk), 256, 0, stream>>>(ws, nchunk, off_part, off_ml);
    if (nchunk == 6)      combine<6><<<1024, 256, 0, stream>>>(ws, off_part, off_ml);
    else if (nchunk == 4) combine<4><<<1024, 256, 0, stream>>>(ws, off_part, off_ml);
    else                  combine<2><<<1024, 256, 0, stream>>>(ws, off_part, off_ml);
    gemm_out<<<dim3(128, 4), 256, 0, stream>>>(x, ws, y);
}

// Round 11
// 98.176 us; speedup vs baseline: 1.6460x; 1.0016x over previous
//
#include <hip/hip_runtime.h>
#include <hip/hip_bf16.h>

// NonLocal block == flash attention (4 heads, N=4096, D=128) + 1x1-conv GEMMs.
// Round 11: flash with triple-buffered staging + raw s_barrier + counted
// s_waitcnt vmcnt(N) (never 0 in steady loop) -- removes the per-tile DMA
// drain of the 2-phase structure. Everything else frozen from R10.

typedef float f32x4 __attribute__((ext_vector_type(4)));
typedef float f32x16 __attribute__((ext_vector_type(16)));
typedef short s16x8 __attribute__((ext_vector_type(8)));
typedef short s16x4 __attribute__((ext_vector_type(4)));

#define B_  4
#define C_  256
#define CI_ 128
#define N_  4096

// workspace layout (bytes)
#define OFF_Q    (8ull  << 20)           // bf16 [B][N][CI]  4 MB (theta^T, scaled)
#define OFF_K    (12ull << 20)           // bf16 [B][N][CI]  4 MB (phi^T)
#define OFF_G    (16ull << 20)           // bf16 [B][CI][N]  4 MB (g, V^T layout)
#define OFF_O    (20ull << 20)           // bf16 [B][N][CI]  4 MB (combined attn out)
#define OFF_WQK  (24ull << 20)
#define OFF_WG   (OFF_WQK + 131072)
#define OFF_WOUT (OFF_WG  + 65536)
#define OFF_BQK  (OFF_WOUT + 65536)
#define OFF_BG   (OFF_BQK + 1024)
#define OFF_BOUT (OFF_BG  + 512)
#define OFF_END  (OFF_BOUT + 1024)       // = 25430528

__device__ inline f32x4 mfma16(s16x8 a, s16x8 b, f32x4 c) {
    return __builtin_amdgcn_mfma_f32_16x16x32_bf16(a, b, c, 0, 0, 0);
}
__device__ inline f32x16 mfma32(s16x8 a, s16x8 b, f32x16 c) {
    return __builtin_amdgcn_mfma_f32_32x32x16_bf16(a, b, c, 0, 0, 0);
}
__device__ inline s16x8 ld8(const __hip_bfloat16* p) { return *(const s16x8*)p; }
__device__ inline float b2f(short u) {
    return __uint_as_float(((unsigned int)(unsigned short)u) << 16);
}
__device__ inline unsigned int pk2(float a, float b) {
    __hip_bfloat162 h;
    h.x = __float2bfloat16(a); h.y = __float2bfloat16(b);
    return *(unsigned int*)&h;
}
__device__ inline void gload_lds16(const void* g, void* l) {
    __builtin_amdgcn_global_load_lds(
        (const __attribute__((address_space(1))) unsigned int*)g,
        (__attribute__((address_space(3))) unsigned int*)l, 16, 0, 0);
}
__device__ inline float fexp2(float x) { return __builtin_amdgcn_exp2f(x); }

// ---------------- weight prep: fp32 -> bf16; fold log2e/sqrt(Ci) into theta
__global__ void prep_weights(const float* wg, const float* bg,
                             const float* wt, const float* bt,
                             const float* wp, const float* bp,
                             const float* wo, const float* bo, char* ws) {
    __hip_bfloat16* Wqk  = (__hip_bfloat16*)(ws + OFF_WQK);
    __hip_bfloat16* Wg   = (__hip_bfloat16*)(ws + OFF_WG);
    __hip_bfloat16* Wout = (__hip_bfloat16*)(ws + OFF_WOUT);
    float* Bqk  = (float*)(ws + OFF_BQK);
    float* Bg   = (float*)(ws + OFF_BG);
    float* Bout = (float*)(ws + OFF_BOUT);
    const float rs = 0.08838834764831845f * 1.4426950408889634f;  // 1/sqrt(128)*log2(e)
    int idx = blockIdx.x * 256 + threadIdx.x;
    if (idx < 65536) {
        int r = idx >> 8, c = idx & 255;
        float v = (r < 128) ? wt[r * 256 + c] * rs : wp[(r - 128) * 256 + c];
        Wqk[idx] = __float2bfloat16(v);
    }
    if (idx < 32768) {
        Wg[idx]   = __float2bfloat16(wg[idx]);
        Wout[idx] = __float2bfloat16(wo[idx]);
    }
    if (idx < 256) { Bqk[idx] = (idx < 128) ? bt[idx] * rs : bp[idx - 128]; Bout[idx] = bo[idx]; }
    if (idx < 128) Bg[idx] = bg[idx];
}

// ---------------- fused transpose + projection (frozen from R10) -----------
__global__ __launch_bounds__(256) void proj(const float* x, char* ws) {
    const __hip_bfloat16* Wqk = (const __hip_bfloat16*)(ws + OFF_WQK);
    const __hip_bfloat16* Wg  = (const __hip_bfloat16*)(ws + OFF_WG);
    const float* Bqk = (const float*)(ws + OFF_BQK);
    const float* Bg  = (const float*)(ws + OFF_BG);
    __hip_bfloat16* Q  = (__hip_bfloat16*)(ws + OFF_Q);
    __hip_bfloat16* Kb = (__hip_bfloat16*)(ws + OFF_K);
    __hip_bfloat16* G  = (__hip_bfloat16*)(ws + OFF_G);

    __shared__ char at[32 * 512];   // [32 n][256 c] bf16, 16B slots XOR-swizzled

    int b = blockIdx.y, n0 = blockIdx.x * 32;
    int t = threadIdx.x;
    int w = t >> 6, l = t & 63, lr = l & 15, lg = l >> 4;

    {
        int cb8 = t >> 5;          // 0..7
        int n = t & 31;
        const float* xcol = x + ((size_t)b * C_) * N_ + n0 + n;
#pragma unroll
        for (int p = 0; p < 32; p++) {
            int c = p * 8 + cb8;
            float v = xcol[(size_t)c * N_];
            int byte0 = n * 512 + ((((c >> 3) ^ (n & 7)) << 4) | ((c & 7) << 1));
            *(unsigned short*)(&at[byte0]) = (unsigned short)(
                *(unsigned int*)&v >> 16) + ((*(unsigned int*)&v >> 15) & 1);
        }
    }
    __syncthreads();

    f32x4 acc[4][2] = {};    // QK path: [of][nf]
    f32x4 accg[2][2] = {};   // G  path: [og][nf]
    int o0q = w * 64, o0g = w * 32;
#pragma unroll
    for (int kk = 0; kk < 8; kk++) {
        s16x8 a[2];
#pragma unroll
        for (int nf = 0; nf < 2; nf++) {
            int row = nf * 16 + lr;
            int s = (4 * kk + lg) ^ (row & 7);
            a[nf] = *(const s16x8*)(&at[row * 512 + s * 16]);
        }
#pragma unroll
        for (int of = 0; of < 4; of++) {
            s16x8 bb = ld8(Wqk + (size_t)(o0q + 16 * of + lr) * C_ + kk * 32 + lg * 8);
            acc[of][0] = mfma16(a[0], bb, acc[of][0]);
            acc[of][1] = mfma16(a[1], bb, acc[of][1]);
        }
#pragma unroll
        for (int og = 0; og < 2; og++) {
            s16x8 ag = ld8(Wg + (size_t)(o0g + 16 * og + lr) * C_ + kk * 32 + lg * 8);
            accg[og][0] = mfma16(ag, a[0], accg[og][0]);
            accg[og][1] = mfma16(ag, a[1], accg[og][1]);
        }
    }
#pragma unroll
    for (int of = 0; of < 4; of++) {
        int o = o0q + 16 * of + lr;
        float bias = Bqk[o];
#pragma unroll
        for (int nf = 0; nf < 2; nf++) {
#pragma unroll
            for (int i = 0; i < 4; i++) {
                int n = n0 + 16 * nf + lg * 4 + i;
                float v = acc[of][nf][i] + bias;
                if (o < 128) Q [(size_t)(b * N_ + n) * CI_ + o]         = __float2bfloat16(v);
                else         Kb[(size_t)(b * N_ + n) * CI_ + (o - 128)] = __float2bfloat16(v);
            }
        }
    }
#pragma unroll
    for (int og = 0; og < 2; og++) {
#pragma unroll
        for (int i = 0; i < 4; i++) {
            int o = o0g + 16 * og + lg * 4 + i;
            float bias = Bg[o];
#pragma unroll
            for (int nf = 0; nf < 2; nf++) {
                int n = n0 + 16 * nf + lr;
                G[(size_t)(b * CI_ + o) * N_ + n] = __float2bfloat16(accg[og][nf][i] + bias);
            }
        }
    }
}

// ---------------- flash v10: 3-buffer staging, counted vmcnt, raw barrier --
// grid: 32 qt * B_ * nchunk blocks of 256 (4 waves); wave = 32 q, KVBLK=32.
__global__ __launch_bounds__(256, 3) void flash10(char* ws, int nchunk,
                                                  unsigned long long off_part,
                                                  unsigned long long off_ml) {
    const __hip_bfloat16* Q  = (const __hip_bfloat16*)(ws + OFF_Q);
    const __hip_bfloat16* Kb = (const __hip_bfloat16*)(ws + OFF_K);
    const __hip_bfloat16* G  = (const __hip_bfloat16*)(ws + OFF_G);
    __hip_bfloat16* OP = (__hip_bfloat16*)(ws + off_part);
    float* ML = (float*)(ws + off_ml);

    __shared__ char kbuf[3][32 * 256];   // K tile [32 j][256 B], slot key (row&7)
    __shared__ char vbuf[3][128 * 64];   // V tile [128 c][64 B], slot key ((c>>1)&3)

    int L = blockIdx.x;
    int npairs = B_ * nchunk;
    int pair = L % npairs, qt = L / npairs;
    int b = pair / nchunk, cz = pair % nchunk;
    int per = 128 / nchunk, rem = 128 % nchunk;
    int jb_t = per * cz + (cz < rem ? cz : rem);
    int sz_t = per + (cz < rem ? 1 : 0);
    int jb = jb_t << 5;
    int nt = sz_t;

    int w = threadIdx.x >> 6, l = threadIdx.x & 63;
    int cl = l & 31, hi = l >> 5;
    int q0 = qt * 128 + w * 32;
    int kkey = (l & 7) << 4;        // K slot key (row = cl)
    int vkey = (l >> 1) & 3;        // V slot key (row c = cb*32+cl)

    // stage = 4 gload_lds ops per wave (2 K rows-groups + 2 V c-groups)
    auto STAGE = [&](int b3, int j0_) {
#pragma unroll
        for (int i = 0; i < 2; i++) {
            int row = w * 8 + i * 4 + (l >> 4);
            int bcol = ((l & 15) << 4) ^ ((row & 7) << 4);
            const char* src = (const char*)Kb + (((size_t)b * N_ + j0_ + row) << 8) + bcol;
            gload_lds16(src, &kbuf[b3][(w * 8 + i * 4) * 256]);
        }
#pragma unroll
        for (int i = 0; i < 2; i++) {
            int c = w * 32 + i * 16 + (l >> 2);
            int srcslot = (l & 3) ^ ((l >> 3) & 3);
            const char* src = (const char*)G + ((((size_t)b * CI_ + c) * N_ + j0_) << 1)
                              + (srcslot << 4);
            gload_lds16(src, &vbuf[b3][(w * 32 + i * 16) * 64]);
        }
    };

    // Q as B-operand (32x32x16): lane holds Q[k = st*16 + hi*8 + e][q = q0+cl]
    s16x8 qb[8];
    {
        const __hip_bfloat16* qrow = Q + ((size_t)b * N_ + q0 + cl) * CI_ + hi * 8;
#pragma unroll
        for (int st = 0; st < 8; st++) qb[st] = ld8(qrow + st * 16);
    }

    f32x16 oacc[4] = {};
    float m_i = 0.f, lsum = 0.f;

    STAGE(0, jb);
    if (nt > 1) STAGE(1, jb + 32);

    int b3 = 0;
    for (int it = 0; it < nt; it++) {
        int j0 = jb + (it << 5);
        // counted wait: own stage for tile `it` complete; next stage stays
        // in flight (never drain to 0 until the last tile)
        if (it + 1 < nt) asm volatile("s_waitcnt vmcnt(4)" ::: "memory");
        else             asm volatile("s_waitcnt vmcnt(0)" ::: "memory");
        __builtin_amdgcn_s_barrier();   // all waves' tile-it data visible; WAR-safe
        if (it + 2 < nt) STAGE((b3 + 2) % 3, j0 + 64);

        const char* kb = kbuf[b3];
        const char* vbb = vbuf[b3];
        f32x16 s = {};
        __builtin_amdgcn_s_setprio(1);
#pragma unroll
        for (int st = 0; st < 8; st++) {
            s16x8 kf = *(const s16x8*)(kb + cl * 256 + ((((st << 1) + hi) << 4) ^ kkey));
            s = mfma32(kf, qb[st], s);
        }
        __builtin_amdgcn_s_setprio(0);
        if (it == 0) {
            float t0 = fmaxf(fmaxf(s[0], s[1]), fmaxf(s[2], s[3]));
            float t1 = fmaxf(fmaxf(s[4], s[5]), fmaxf(s[6], s[7]));
            float t2 = fmaxf(fmaxf(s[8], s[9]), fmaxf(s[10], s[11]));
            float t3 = fmaxf(fmaxf(s[12], s[13]), fmaxf(s[14], s[15]));
            float tm = fmaxf(fmaxf(t0, t1), fmaxf(t2, t3));
            tm = fmaxf(tm, __shfl_xor(tm, 32));
            m_i = tm;
        }
#pragma unroll
        for (int r = 0; r < 16; r++) s[r] = fexp2(s[r] - m_i);
        lsum += ((s[0] + s[1]) + (s[2] + s[3])) + ((s[4] + s[5]) + (s[6] + s[7]))
              + ((s[8] + s[9]) + (s[10] + s[11])) + ((s[12] + s[13]) + (s[14] + s[15]));
        union { unsigned int u[4]; s16x8 v; } pa0, pa1;
#pragma unroll
        for (int i = 0; i < 4; i++) {
            pa0.u[i] = pk2(s[2 * i], s[2 * i + 1]);
            pa1.u[i] = pk2(s[8 + 2 * i], s[9 + 2 * i]);
        }
        __builtin_amdgcn_s_setprio(1);
#pragma unroll
        for (int u = 0; u < 2; u++) {
            s16x8 pa = u ? pa1.v : pa0.v;
#pragma unroll
            for (int cb = 0; cb < 4; cb++) {
                const char* base = vbb + ((cb * 32 + cl) << 6) + hi * 8;
                union { s16x4 h[2]; s16x8 v; } vf;
                vf.h[0] = *(const s16x4*)(base + ((((u << 1))     ^ vkey) << 4));
                vf.h[1] = *(const s16x4*)(base + ((((u << 1) | 1) ^ vkey) << 4));
                oacc[cb] = mfma32(pa, vf.v, oacc[cb]);
            }
        }
        __builtin_amdgcn_s_setprio(0);
        b3 = (b3 + 1) % 3;
    }
    lsum += __shfl_xor(lsum, 32);
#pragma unroll
    for (int cb = 0; cb < 4; cb++) {
#pragma unroll
        for (int r = 0; r < 16; r++) {
            int q = q0 + (r & 3) + 8 * (r >> 2) + 4 * hi;
            OP[((size_t)(cz * B_ + b) * N_ + q) * CI_ + cb * 32 + cl] =
                __float2bfloat16(oacc[cb][r]);
        }
    }
    if (l < 32) {
        size_t mi = ((size_t)(cz * B_ + b) * N_ + q0 + l) * 2;
        ML[mi] = m_i;
        ML[mi + 1] = lsum;
    }
}

// ---------------- combine split-KV partials -> O (frozen) ------------------
template <int NC>
__global__ __launch_bounds__(256) void combine(char* ws,
                                               unsigned long long off_part,
                                               unsigned long long off_ml) {
    const __hip_bfloat16* OP = (const __hip_bfloat16*)(ws + off_part);
    const float* ML = (const float*)(ws + off_ml);
    __hip_bfloat16* O = (__hip_bfloat16*)(ws + OFF_O);
    int idx = blockIdx.x * 256 + threadIdx.x;      // B*N*16 threads
    int cg = idx & 15, n = (idx >> 4) & (N_ - 1), b = idx >> 16;
    float mz[NC], lz[NC], M = -1e30f;
#pragma unroll
    for (int z = 0; z < NC; z++) {
        size_t mi = ((size_t)(z * B_ + b) * N_ + n) * 2;
        mz[z] = ML[mi]; lz[z] = ML[mi + 1];
        M = fmaxf(M, mz[z]);
    }
    float Lsum = 0.f, wz[NC];
#pragma unroll
    for (int z = 0; z < NC; z++) { wz[z] = fexp2(mz[z] - M); Lsum += lz[z] * wz[z]; }
    float inv = 1.f / Lsum;
    float o[8] = {};
#pragma unroll
    for (int z = 0; z < NC; z++) {
        s16x8 v = ld8(OP + ((size_t)(z * B_ + b) * N_ + n) * CI_ + cg * 8);
        float wv = wz[z] * inv;
#pragma unroll
        for (int i = 0; i < 8; i++) o[i] += wv * b2f(v[i]);
    }
    s16x8 r;
#pragma unroll
    for (int i = 0; i < 8; i++) {
        __hip_bfloat16 h = __float2bfloat16(o[i]);
        r[i] = *(short*)&h;
    }
    *(s16x8*)(O + ((size_t)b * N_ + n) * CI_ + cg * 8) = r;
}

// ---------------- out projection + bias + residual (frozen from R10) -------
__global__ __launch_bounds__(256) void gemm_out(const float* x, char* ws, float* y) {
    const __hip_bfloat16* Ob = (const __hip_bfloat16*)(ws + OFF_O);
    const __hip_bfloat16* Wo = (const __hip_bfloat16*)(ws + OFF_WOUT);
    const float* Bout = (const float*)(ws + OFF_BOUT);
    int b = blockIdx.y;
    int w = threadIdx.x >> 6, l = threadIdx.x & 63, lr = l & 15, lg = l >> 4;
    int n0 = blockIdx.x * 32;
    int o0 = w * 64;
    f32x4 acc[4][2] = {};   // [of][nf]
#pragma unroll
    for (int kk = 0; kk < 4; kk++) {
        s16x8 bb[2];
#pragma unroll
        for (int nf = 0; nf < 2; nf++)
            bb[nf] = ld8(Ob + (size_t)(b * N_ + n0 + 16 * nf + lr) * CI_ + kk * 32 + lg * 8);
#pragma unroll
        for (int of = 0; of < 4; of++) {
            s16x8 a = ld8(Wo + (size_t)(o0 + 16 * of + lr) * CI_ + kk * 32 + lg * 8);
#pragma unroll
            for (int nf = 0; nf < 2; nf++)
                acc[of][nf] = mfma16(a, bb[nf], acc[of][nf]);
        }
    }
#pragma unroll
    for (int of = 0; of < 4; of++) {
#pragma unroll
        for (int i = 0; i < 4; i++) {
            int o = o0 + 16 * of + lg * 4 + i;
            float bias = Bout[o];
#pragma unroll
            for (int nf = 0; nf < 2; nf++) {
                int n = n0 + 16 * nf + lr;
                size_t idx = (size_t)(b * C_ + o) * N_ + n;
                y[idx] = acc[of][nf][i] + bias + x[idx];
            }
        }
    }
}

extern "C" void kernel_launch(void* const* d_in, const int* in_sizes, int n_in,
                              void* d_out, int out_size, void* d_ws, size_t ws_size,
                              hipStream_t stream) {
    const float* x  = (const float*)d_in[0];
    const float* wg = (const float*)d_in[1];
    const float* bg = (const float*)d_in[2];
    const float* wt = (const float*)d_in[3];
    const float* bt = (const float*)d_in[4];
    const float* wp = (const float*)d_in[5];
    const float* bp = (const float*)d_in[6];
    const float* wo = (const float*)d_in[7];
    const float* bo = (const float*)d_in[8];
    char* ws = (char*)d_ws;
    float* y = (float*)d_out;

    // split-KV factor: 6 fills 256 CUs at 3 blocks/CU exactly (768 blocks)
    unsigned long long need6 = OFF_END + (24ull << 20) + (1ull << 20);
    unsigned long long need4 = OFF_END + (16ull << 20) + (1ull << 20);
    int nchunk;
    unsigned long long off_part, off_ml;
    if (ws_size >= need6) {
        nchunk = 6; off_part = OFF_END; off_ml = OFF_END + (24ull << 20);
    } else if (ws_size >= need4) {
        nchunk = 4; off_part = OFF_END; off_ml = OFF_END + (16ull << 20);
    } else {
        nchunk = 2; off_part = 0ull; off_ml = OFF_END;   // partials in dead low region
    }

    prep_weights<<<256, 256, 0, stream>>>(wg, bg, wt, bt, wp, bp, wo, bo, ws);
    proj<<<dim3(128, 4), 256, 0, stream>>>(x, ws);
    flash10<<<dim3(32 * B_ * nchunk), 256, 0, stream>>>(ws, nchunk, off_part, off_ml);
    if (nchunk == 6)      combine<6><<<1024, 256, 0, stream>>>(ws, off_part, off_ml);
    else if (nchunk == 4) combine<4><<<1024, 256, 0, stream>>>(ws, off_part, off_ml);
    else                  combine<2><<<1024, 256, 0, stream>>>(ws, off_part, off_ml);
    gemm_out<<<dim3(128, 4), 256, 0, stream>>>(x, ws, y);
}

// Round 12
// 95.769 us; speedup vs baseline: 1.6874x; 1.0251x over previous
//
#include <hip/hip_runtime.h>
#include <hip/hip_bf16.h>

// NonLocal block == flash attention (4 heads, N=4096, D=128) + 1x1-conv GEMMs.
// Round 12: flash = flash9 (2-buffer) + split QK accumulation chain (2x ILP);
// proj staging vectorized (float4 loads, b32 packed LDS writes).

typedef float f32x4 __attribute__((ext_vector_type(4)));
typedef float f32x16 __attribute__((ext_vector_type(16)));
typedef short s16x8 __attribute__((ext_vector_type(8)));
typedef short s16x4 __attribute__((ext_vector_type(4)));

#define B_  4
#define C_  256
#define CI_ 128
#define N_  4096

// workspace layout (bytes)
#define OFF_Q    (8ull  << 20)           // bf16 [B][N][CI]  4 MB (theta^T, scaled)
#define OFF_K    (12ull << 20)           // bf16 [B][N][CI]  4 MB (phi^T)
#define OFF_G    (16ull << 20)           // bf16 [B][CI][N]  4 MB (g, V^T layout)
#define OFF_O    (20ull << 20)           // bf16 [B][N][CI]  4 MB (combined attn out)
#define OFF_WQK  (24ull << 20)
#define OFF_WG   (OFF_WQK + 131072)
#define OFF_WOUT (OFF_WG  + 65536)
#define OFF_BQK  (OFF_WOUT + 65536)
#define OFF_BG   (OFF_BQK + 1024)
#define OFF_BOUT (OFF_BG  + 512)
#define OFF_END  (OFF_BOUT + 1024)       // = 25430528

__device__ inline f32x4 mfma16(s16x8 a, s16x8 b, f32x4 c) {
    return __builtin_amdgcn_mfma_f32_16x16x32_bf16(a, b, c, 0, 0, 0);
}
__device__ inline f32x16 mfma32(s16x8 a, s16x8 b, f32x16 c) {
    return __builtin_amdgcn_mfma_f32_32x32x16_bf16(a, b, c, 0, 0, 0);
}
__device__ inline s16x8 ld8(const __hip_bfloat16* p) { return *(const s16x8*)p; }
__device__ inline float b2f(short u) {
    return __uint_as_float(((unsigned int)(unsigned short)u) << 16);
}
__device__ inline unsigned int pk2(float a, float b) {
    __hip_bfloat162 h;
    h.x = __float2bfloat16(a); h.y = __float2bfloat16(b);
    return *(unsigned int*)&h;
}
__device__ inline void gload_lds16(const void* g, void* l) {
    __builtin_amdgcn_global_load_lds(
        (const __attribute__((address_space(1))) unsigned int*)g,
        (__attribute__((address_space(3))) unsigned int*)l, 16, 0, 0);
}
__device__ inline float fexp2(float x) { return __builtin_amdgcn_exp2f(x); }

// ---------------- weight prep: fp32 -> bf16; fold log2e/sqrt(Ci) into theta
__global__ void prep_weights(const float* wg, const float* bg,
                             const float* wt, const float* bt,
                             const float* wp, const float* bp,
                             const float* wo, const float* bo, char* ws) {
    __hip_bfloat16* Wqk  = (__hip_bfloat16*)(ws + OFF_WQK);
    __hip_bfloat16* Wg   = (__hip_bfloat16*)(ws + OFF_WG);
    __hip_bfloat16* Wout = (__hip_bfloat16*)(ws + OFF_WOUT);
    float* Bqk  = (float*)(ws + OFF_BQK);
    float* Bg   = (float*)(ws + OFF_BG);
    float* Bout = (float*)(ws + OFF_BOUT);
    const float rs = 0.08838834764831845f * 1.4426950408889634f;  // 1/sqrt(128)*log2(e)
    int idx = blockIdx.x * 256 + threadIdx.x;
    if (idx < 65536) {
        int r = idx >> 8, c = idx & 255;
        float v = (r < 128) ? wt[r * 256 + c] * rs : wp[(r - 128) * 256 + c];
        Wqk[idx] = __float2bfloat16(v);
    }
    if (idx < 32768) {
        Wg[idx]   = __float2bfloat16(wg[idx]);
        Wout[idx] = __float2bfloat16(wo[idx]);
    }
    if (idx < 256) { Bqk[idx] = (idx < 128) ? bt[idx] * rs : bp[idx - 128]; Bout[idx] = bo[idx]; }
    if (idx < 128) Bg[idx] = bg[idx];
}

// ---------------- fused transpose + projection: Q, K, G from x -------------
// grid (128, B_), block 256 (4 waves). Stage x[b][:, n0..n0+32] transposed
// into at[32 n][256 c] bf16 (16B-slot XOR swizzle). Vectorized: float4 loads
// over n for c-pairs, packed b32 LDS writes.
__global__ __launch_bounds__(256) void proj(const float* x, char* ws) {
    const __hip_bfloat16* Wqk = (const __hip_bfloat16*)(ws + OFF_WQK);
    const __hip_bfloat16* Wg  = (const __hip_bfloat16*)(ws + OFF_WG);
    const float* Bqk = (const float*)(ws + OFF_BQK);
    const float* Bg  = (const float*)(ws + OFF_BG);
    __hip_bfloat16* Q  = (__hip_bfloat16*)(ws + OFF_Q);
    __hip_bfloat16* Kb = (__hip_bfloat16*)(ws + OFF_K);
    __hip_bfloat16* G  = (__hip_bfloat16*)(ws + OFF_G);

    __shared__ char at[32 * 512];   // [32 n][256 c] bf16, 16B slots XOR-swizzled

    int b = blockIdx.y, n0 = blockIdx.x * 32;
    int t = threadIdx.x;
    int w = t >> 6, l = t & 63, lr = l & 15, lg = l >> 4;

    // transpose-stage: thread handles c-pair (c0,c0+1) x 4 consecutive n
    {
        int n4 = (t & 7) * 4;              // n offset within tile
        int cp = t >> 3;                   // 0..31 c-pair base index
        const float* xb = x + ((size_t)b * C_) * N_ + n0 + n4;
#pragma unroll
        for (int p = 0; p < 4; p++) {
            int c0 = (p * 32 + cp) * 2;
            f32x4 vA = *(const f32x4*)(xb + (size_t)c0 * N_);
            f32x4 vB = *(const f32x4*)(xb + (size_t)(c0 + 1) * N_);
            int slot = c0 >> 3, coff = (c0 & 7) << 1;
#pragma unroll
            for (int i = 0; i < 4; i++) {
                int n = n4 + i;
                *(unsigned int*)(&at[n * 512 + ((slot ^ (n & 7)) << 4) + coff]) =
                    pk2(vA[i], vB[i]);
            }
        }
    }
    __syncthreads();

    f32x4 acc[4][2] = {};    // QK path: [of][nf]
    f32x4 accg[2][2] = {};   // G  path: [og][nf]
    int o0q = w * 64, o0g = w * 32;
#pragma unroll
    for (int kk = 0; kk < 8; kk++) {
        s16x8 a[2];
#pragma unroll
        for (int nf = 0; nf < 2; nf++) {
            int row = nf * 16 + lr;
            int s = (4 * kk + lg) ^ (row & 7);
            a[nf] = *(const s16x8*)(&at[row * 512 + s * 16]);
        }
#pragma unroll
        for (int of = 0; of < 4; of++) {
            s16x8 bb = ld8(Wqk + (size_t)(o0q + 16 * of + lr) * C_ + kk * 32 + lg * 8);
            acc[of][0] = mfma16(a[0], bb, acc[of][0]);
            acc[of][1] = mfma16(a[1], bb, acc[of][1]);
        }
#pragma unroll
        for (int og = 0; og < 2; og++) {
            s16x8 ag = ld8(Wg + (size_t)(o0g + 16 * og + lr) * C_ + kk * 32 + lg * 8);
            accg[og][0] = mfma16(ag, a[0], accg[og][0]);
            accg[og][1] = mfma16(ag, a[1], accg[og][1]);
        }
    }
#pragma unroll
    for (int of = 0; of < 4; of++) {
        int o = o0q + 16 * of + lr;
        float bias = Bqk[o];
#pragma unroll
        for (int nf = 0; nf < 2; nf++) {
#pragma unroll
            for (int i = 0; i < 4; i++) {
                int n = n0 + 16 * nf + lg * 4 + i;
                float v = acc[of][nf][i] + bias;
                if (o < 128) Q [(size_t)(b * N_ + n) * CI_ + o]         = __float2bfloat16(v);
                else         Kb[(size_t)(b * N_ + n) * CI_ + (o - 128)] = __float2bfloat16(v);
            }
        }
    }
#pragma unroll
    for (int og = 0; og < 2; og++) {
#pragma unroll
        for (int i = 0; i < 4; i++) {
            int o = o0g + 16 * og + lg * 4 + i;
            float bias = Bg[o];
#pragma unroll
            for (int nf = 0; nf < 2; nf++) {
                int n = n0 + 16 * nf + lr;
                G[(size_t)(b * CI_ + o) * N_ + n] = __float2bfloat16(accg[og][nf][i] + bias);
            }
        }
    }
}

// ---------------- flash v11: 32x32x16, in-reg P, split QK chains -----------
// grid: 32 qt * B_ * nchunk blocks of 256 (4 waves); wave = 32 q, KVBLK=32.
__global__ __launch_bounds__(256, 3) void flash11(char* ws, int nchunk,
                                                  unsigned long long off_part,
                                                  unsigned long long off_ml) {
    const __hip_bfloat16* Q  = (const __hip_bfloat16*)(ws + OFF_Q);
    const __hip_bfloat16* Kb = (const __hip_bfloat16*)(ws + OFF_K);
    const __hip_bfloat16* G  = (const __hip_bfloat16*)(ws + OFF_G);
    __hip_bfloat16* OP = (__hip_bfloat16*)(ws + off_part);
    float* ML = (float*)(ws + off_ml);

    __shared__ char kbuf[2][32 * 256];   // K tile [32 j][256 B], slot key (row&7)
    __shared__ char vbuf[2][128 * 64];   // V tile [128 c][64 B], slot key ((c>>1)&3)

    int L = blockIdx.x;
    int npairs = B_ * nchunk;
    int pair = L % npairs, qt = L / npairs;
    int b = pair / nchunk, cz = pair % nchunk;
    int per = 128 / nchunk, rem = 128 % nchunk;
    int jb_t = per * cz + (cz < rem ? cz : rem);
    int sz_t = per + (cz < rem ? 1 : 0);
    int jb = jb_t << 5, je = jb + (sz_t << 5);

    int w = threadIdx.x >> 6, l = threadIdx.x & 63;
    int cl = l & 31, hi = l >> 5;
    int q0 = qt * 128 + w * 32;
    int kkey = (l & 7) << 4;        // K slot key (row = cl)
    int vkey = (l >> 1) & 3;        // V slot key (row c = cb*32+cl)

    auto STAGE = [&](int pb_, int j0_) {
#pragma unroll
        for (int i = 0; i < 2; i++) {
            int row = w * 8 + i * 4 + (l >> 4);
            int bcol = ((l & 15) << 4) ^ ((row & 7) << 4);
            const char* src = (const char*)Kb + (((size_t)b * N_ + j0_ + row) << 8) + bcol;
            gload_lds16(src, &kbuf[pb_][(w * 8 + i * 4) * 256]);
        }
#pragma unroll
        for (int i = 0; i < 2; i++) {
            int c = w * 32 + i * 16 + (l >> 2);
            int srcslot = (l & 3) ^ ((l >> 3) & 3);
            const char* src = (const char*)G + ((((size_t)b * CI_ + c) * N_ + j0_) << 1)
                              + (srcslot << 4);
            gload_lds16(src, &vbuf[pb_][(w * 32 + i * 16) * 64]);
        }
    };

    // Q as B-operand (32x32x16): lane holds Q[k = st*16 + hi*8 + e][q = q0+cl]
    s16x8 qb[8];
    {
        const __hip_bfloat16* qrow = Q + ((size_t)b * N_ + q0 + cl) * CI_ + hi * 8;
#pragma unroll
        for (int st = 0; st < 8; st++) qb[st] = ld8(qrow + st * 16);
    }

    f32x16 oacc[4] = {};
    float m_i = 0.f, lsum = 0.f;

    STAGE(0, jb);
    __syncthreads();
    int pb = 0;

    for (int j0 = jb; j0 < je; j0 += 32) {
        if (j0 + 32 < je) STAGE(pb ^ 1, j0 + 32);
        const char* kb = kbuf[pb];
        const char* vbb = vbuf[pb];
        // S^T[j][q] = K Q : two independent 4-deep chains (2x MFMA ILP)
        f32x16 sa = {}, sb = {};
        __builtin_amdgcn_s_setprio(1);
#pragma unroll
        for (int st = 0; st < 4; st++) {
            s16x8 kfa = *(const s16x8*)(kb + cl * 256 + ((((st << 1) + hi) << 4) ^ kkey));
            s16x8 kfb = *(const s16x8*)(kb + cl * 256 + (((((st + 4) << 1) + hi) << 4) ^ kkey));
            sa = mfma32(kfa, qb[st], sa);
            sb = mfma32(kfb, qb[st + 4], sb);
        }
        __builtin_amdgcn_s_setprio(0);
        f32x16 s = sa + sb;
        // one-shot max from first tile
        if (j0 == jb) {
            float t0 = fmaxf(fmaxf(s[0], s[1]), fmaxf(s[2], s[3]));
            float t1 = fmaxf(fmaxf(s[4], s[5]), fmaxf(s[6], s[7]));
            float t2 = fmaxf(fmaxf(s[8], s[9]), fmaxf(s[10], s[11]));
            float t3 = fmaxf(fmaxf(s[12], s[13]), fmaxf(s[14], s[15]));
            float tm = fmaxf(fmaxf(t0, t1), fmaxf(t2, t3));
            tm = fmaxf(tm, __shfl_xor(tm, 32));
            m_i = tm;
        }
#pragma unroll
        for (int r = 0; r < 16; r++) s[r] = fexp2(s[r] - m_i);
        lsum += ((s[0] + s[1]) + (s[2] + s[3])) + ((s[4] + s[5]) + (s[6] + s[7]))
              + ((s[8] + s[9]) + (s[10] + s[11])) + ((s[12] + s[13]) + (s[14] + s[15]));
        union { unsigned int u[4]; s16x8 v; } pa0, pa1;
#pragma unroll
        for (int i = 0; i < 4; i++) {
            pa0.u[i] = pk2(s[2 * i], s[2 * i + 1]);
            pa1.u[i] = pk2(s[8 + 2 * i], s[9 + 2 * i]);
        }
        __builtin_amdgcn_s_setprio(1);
#pragma unroll
        for (int u = 0; u < 2; u++) {
            s16x8 pa = u ? pa1.v : pa0.v;
#pragma unroll
            for (int cb = 0; cb < 4; cb++) {
                const char* base = vbb + ((cb * 32 + cl) << 6) + hi * 8;
                union { s16x4 h[2]; s16x8 v; } vf;
                vf.h[0] = *(const s16x4*)(base + ((((u << 1))     ^ vkey) << 4));
                vf.h[1] = *(const s16x4*)(base + ((((u << 1) | 1) ^ vkey) << 4));
                oacc[cb] = mfma32(pa, vf.v, oacc[cb]);
            }
        }
        __builtin_amdgcn_s_setprio(0);
        __syncthreads();
        pb ^= 1;
    }
    lsum += __shfl_xor(lsum, 32);
#pragma unroll
    for (int cb = 0; cb < 4; cb++) {
#pragma unroll
        for (int r = 0; r < 16; r++) {
            int q = q0 + (r & 3) + 8 * (r >> 2) + 4 * hi;
            OP[((size_t)(cz * B_ + b) * N_ + q) * CI_ + cb * 32 + cl] =
                __float2bfloat16(oacc[cb][r]);
        }
    }
    if (l < 32) {
        size_t mi = ((size_t)(cz * B_ + b) * N_ + q0 + l) * 2;
        ML[mi] = m_i;
        ML[mi + 1] = lsum;
    }
}

// ---------------- combine split-KV partials -> O (frozen) ------------------
template <int NC>
__global__ __launch_bounds__(256) void combine(char* ws,
                                               unsigned long long off_part,
                                               unsigned long long off_ml) {
    const __hip_bfloat16* OP = (const __hip_bfloat16*)(ws + off_part);
    const float* ML = (const float*)(ws + off_ml);
    __hip_bfloat16* O = (__hip_bfloat16*)(ws + OFF_O);
    int idx = blockIdx.x * 256 + threadIdx.x;      // B*N*16 threads
    int cg = idx & 15, n = (idx >> 4) & (N_ - 1), b = idx >> 16;
    float mz[NC], lz[NC], M = -1e30f;
#pragma unroll
    for (int z = 0; z < NC; z++) {
        size_t mi = ((size_t)(z * B_ + b) * N_ + n) * 2;
        mz[z] = ML[mi]; lz[z] = ML[mi + 1];
        M = fmaxf(M, mz[z]);
    }
    float Lsum = 0.f, wz[NC];
#pragma unroll
    for (int z = 0; z < NC; z++) { wz[z] = fexp2(mz[z] - M); Lsum += lz[z] * wz[z]; }
    float inv = 1.f / Lsum;
    float o[8] = {};
#pragma unroll
    for (int z = 0; z < NC; z++) {
        s16x8 v = ld8(OP + ((size_t)(z * B_ + b) * N_ + n) * CI_ + cg * 8);
        float wv = wz[z] * inv;
#pragma unroll
        for (int i = 0; i < 8; i++) o[i] += wv * b2f(v[i]);
    }
    s16x8 r;
#pragma unroll
    for (int i = 0; i < 8; i++) {
        __hip_bfloat16 h = __float2bfloat16(o[i]);
        r[i] = *(short*)&h;
    }
    *(s16x8*)(O + ((size_t)b * N_ + n) * CI_ + cg * 8) = r;
}

// ---------------- out projection + bias + residual (frozen from R10) -------
__global__ __launch_bounds__(256) void gemm_out(const float* x, char* ws, float* y) {
    const __hip_bfloat16* Ob = (const __hip_bfloat16*)(ws + OFF_O);
    const __hip_bfloat16* Wo = (const __hip_bfloat16*)(ws + OFF_WOUT);
    const float* Bout = (const float*)(ws + OFF_BOUT);
    int b = blockIdx.y;
    int w = threadIdx.x >> 6, l = threadIdx.x & 63, lr = l & 15, lg = l >> 4;
    int n0 = blockIdx.x * 32;
    int o0 = w * 64;
    f32x4 acc[4][2] = {};   // [of][nf]
#pragma unroll
    for (int kk = 0; kk < 4; kk++) {
        s16x8 bb[2];
#pragma unroll
        for (int nf = 0; nf < 2; nf++)
            bb[nf] = ld8(Ob + (size_t)(b * N_ + n0 + 16 * nf + lr) * CI_ + kk * 32 + lg * 8);
#pragma unroll
        for (int of = 0; of < 4; of++) {
            s16x8 a = ld8(Wo + (size_t)(o0 + 16 * of + lr) * CI_ + kk * 32 + lg * 8);
#pragma unroll
            for (int nf = 0; nf < 2; nf++)
                acc[of][nf] = mfma16(a, bb[nf], acc[of][nf]);
        }
    }
#pragma unroll
    for (int of = 0; of < 4; of++) {
#pragma unroll
        for (int i = 0; i < 4; i++) {
            int o = o0 + 16 * of + lg * 4 + i;
            float bias = Bout[o];
#pragma unroll
            for (int nf = 0; nf < 2; nf++) {
                int n = n0 + 16 * nf + lr;
                size_t idx = (size_t)(b * C_ + o) * N_ + n;
                y[idx] = acc[of][nf][i] + bias + x[idx];
            }
        }
    }
}

extern "C" void kernel_launch(void* const* d_in, const int* in_sizes, int n_in,
                              void* d_out, int out_size, void* d_ws, size_t ws_size,
                              hipStream_t stream) {
    const float* x  = (const float*)d_in[0];
    const float* wg = (const float*)d_in[1];
    const float* bg = (const float*)d_in[2];
    const float* wt = (const float*)d_in[3];
    const float* bt = (const float*)d_in[4];
    const float* wp = (const float*)d_in[5];
    const float* bp = (const float*)d_in[6];
    const float* wo = (const float*)d_in[7];
    const float* bo = (const float*)d_in[8];
    char* ws = (char*)d_ws;
    float* y = (float*)d_out;

    // split-KV factor: 6 fills 256 CUs at 3 blocks/CU exactly (768 blocks)
    unsigned long long need6 = OFF_END + (24ull << 20) + (1ull << 20);
    unsigned long long need4 = OFF_END + (16ull << 20) + (1ull << 20);
    int nchunk;
    unsigned long long off_part, off_ml;
    if (ws_size >= need6) {
        nchunk = 6; off_part = OFF_END; off_ml = OFF_END + (24ull << 20);
    } else if (ws_size >= need4) {
        nchunk = 4; off_part = OFF_END; off_ml = OFF_END + (16ull << 20);
    } else {
        nchunk = 2; off_part = 0ull; off_ml = OFF_END;   // partials in dead low region
    }

    prep_weights<<<256, 256, 0, stream>>>(wg, bg, wt, bt, wp, bp, wo, bo, ws);
    proj<<<dim3(128, 4), 256, 0, stream>>>(x, ws);
    flash11<<<dim3(32 * B_ * nchunk), 256, 0, stream>>>(ws, nchunk, off_part, off_ml);
    if (nchunk == 6)      combine<6><<<1024, 256, 0, stream>>>(ws, off_part, off_ml);
    else if (nchunk == 4) combine<4><<<1024, 256, 0, stream>>>(ws, off_part, off_ml);
    else                  combine<2><<<1024, 256, 0, stream>>>(ws, off_part, off_ml);
    gemm_out<<<dim3(128, 4), 256, 0, stream>>>(x, ws, y);
}